// Round 1
// baseline (649.332 us; speedup 1.0000x reference)
//
#include <hip/hip_runtime.h>

#define N_NODES 100000
#define N_EDGES 1600000
#define HID 128
#define OUT_DIM 64
#define CAP 64   // max in-degree capacity (max expected ~40 for this graph)

// ---------------- embed lookup: x0[i] = embed[ids[i]] ----------------
__global__ __launch_bounds__(256) void embed_k(const int* __restrict__ ids,
                                               const float* __restrict__ emb,
                                               float* __restrict__ x) {
    int i = blockIdx.x * 256 + threadIdx.x;   // float4 granularity
    int node = i >> 5, f = i & 31;            // 32 float4 per row
    if (node < N_NODES) {
        ((float4*)x)[node * 32 + f] = ((const float4*)emb)[ids[node] * 32 + f];
    }
}

// ---------------- CSR-ish padded bucket build ----------------
__global__ __launch_bounds__(256) void scatter_k(const int* __restrict__ src,
                                                 const int* __restrict__ dst,
                                                 int* __restrict__ cnt,
                                                 int* __restrict__ padded) {
    int e = blockIdx.x * 256 + threadIdx.x;
    if (e < N_EDGES) {
        int d = dst[e];
        int pos = atomicAdd(&cnt[d], 1);
        if (pos < CAP) padded[d * CAP + pos] = src[e];
    }
}

// ---------------- fused weights: Wf = w1@w2, Bf = b1@w2 + b2 ----------------
__global__ __launch_bounds__(128) void fusew_k(const float* __restrict__ w1,
                                               const float* __restrict__ b1,
                                               const float* __restrict__ w2,
                                               const float* __restrict__ b2,
                                               float* __restrict__ Wf,
                                               float* __restrict__ Bf) {
    int j = threadIdx.x;
    int i = blockIdx.x;
    if (i < HID) {
        float s = 0.f;
        for (int k = 0; k < HID; ++k) s = fmaf(w1[i * HID + k], w2[k * HID + j], s);
        Wf[i * HID + j] = s;
    } else {
        float s = b2[j];
        for (int k = 0; k < HID; ++k) s = fmaf(b1[k], w2[k * HID + j], s);
        Bf[j] = s;
    }
}

// ---------------- aggregation: out[n] = (1+eps)*x[n] + sum_{e: dst=n} x[src(e)] ----------------
__global__ __launch_bounds__(256) void agg_k(const float* __restrict__ xin,
                                             float* __restrict__ outp,
                                             const int* __restrict__ cnt,
                                             const int* __restrict__ padded,
                                             const float* __restrict__ epsp) {
    int node = blockIdx.x * 4 + (threadIdx.x >> 6);
    int lane = threadIdx.x & 63;
    int deg = cnt[node];
    if (deg > CAP) deg = CAP;
    int my_src = padded[node * CAP + lane];   // full CAP slot always allocated
    const float2* x2 = (const float2*)xin;
    float e1 = 1.0f + epsp[0];
    float2 self = x2[node * 64 + lane];
    float2 acc = make_float2(self.x * e1, self.y * e1);
    for (int j = 0; j < deg; ++j) {
        int s = __shfl(my_src, j);
        float2 v = x2[(long)s * 64 + lane];
        acc.x += v.x;
        acc.y += v.y;
    }
    ((float2*)outp)[node * 64 + lane] = acc;
}

// ---------------- GEMM: Out = [relu](A @ W + bias), A:[M][HID], W:[HID][NC] ----------------
template <int NC, bool RELU>
__global__ __launch_bounds__(256) void gemm_k(const float* __restrict__ A,
                                              const float* __restrict__ W,
                                              const float* __restrict__ bias,
                                              float* __restrict__ Out, int M) {
    constexpr int TX = NC / 8;        // threads along columns (8 cols each)
    constexpr int TY = 256 / TX;      // thread groups along rows
    constexpr int ROWS = TY * 4;      // rows per block
    __shared__ float As[ROWS][HID + 4];
    __shared__ float Ws[HID][NC];

    int tid = threadIdx.x;
    int tx = tid % TX, ty = tid / TX;
    int row0 = blockIdx.x * ROWS;

    // stage W (HID*NC floats)
    constexpr int W4 = HID * NC / 4;
    for (int i = tid; i < W4; i += 256) {
        ((float4*)&Ws[0][0])[i] = ((const float4*)W)[i];
    }
    // stage A tile
    for (int i = tid; i < ROWS * 32; i += 256) {
        int r = i >> 5, c4 = i & 31;
        int gr = row0 + r;
        float4 v = (gr < M) ? ((const float4*)A)[(long)gr * 32 + c4]
                            : make_float4(0.f, 0.f, 0.f, 0.f);
        *(float4*)&As[r][c4 * 4] = v;
    }
    __syncthreads();

    float acc[4][8];
#pragma unroll
    for (int r = 0; r < 4; ++r)
#pragma unroll
        for (int c = 0; c < 8; ++c) acc[r][c] = 0.f;

    int colb = tx * 8;
#pragma unroll 8
    for (int k = 0; k < HID; ++k) {
        float w[8];
#pragma unroll
        for (int c = 0; c < 8; ++c) w[c] = Ws[k][colb + c];
#pragma unroll
        for (int r = 0; r < 4; ++r) {
            float a = As[ty * 4 + r][k];
#pragma unroll
            for (int c = 0; c < 8; ++c) acc[r][c] = fmaf(a, w[c], acc[r][c]);
        }
    }

#pragma unroll
    for (int r = 0; r < 4; ++r) {
        int gr = row0 + ty * 4 + r;
        if (gr < M) {
            float o[8];
#pragma unroll
            for (int c = 0; c < 8; ++c) {
                float v = acc[r][c] + bias[colb + c];
                o[c] = (RELU && v < 0.f) ? 0.f : v;
            }
            float4* dst = (float4*)&Out[(long)gr * NC + colb];
            dst[0] = make_float4(o[0], o[1], o[2], o[3]);
            dst[1] = make_float4(o[4], o[5], o[6], o[7]);
        }
    }
}

extern "C" void kernel_launch(void* const* d_in, const int* in_sizes, int n_in,
                              void* d_out, int out_size, void* d_ws, size_t ws_size,
                              hipStream_t stream) {
    const int*   x_ids    = (const int*)d_in[0];
    const int*   edge_src = (const int*)d_in[1];
    const int*   edge_dst = (const int*)d_in[2];
    const float* embed    = (const float*)d_in[3];
    const float* eps0     = (const float*)d_in[4];
    const float* w1_0     = (const float*)d_in[5];
    const float* b1_0     = (const float*)d_in[6];
    const float* w2_0     = (const float*)d_in[7];
    const float* b2_0     = (const float*)d_in[8];
    const float* eps1     = (const float*)d_in[9];
    const float* w1_1     = (const float*)d_in[10];
    const float* b1_1     = (const float*)d_in[11];
    const float* w2_1     = (const float*)d_in[12];
    const float* b2_1     = (const float*)d_in[13];
    const float* wp       = (const float*)d_in[14];
    const float* bp       = (const float*)d_in[15];

    float* out   = (float*)d_out;
    float* OUTX  = out + (size_t)N_NODES * OUT_DIM;   // x region of d_out (also work buf)

    char* ws = (char*)d_ws;
    float* WS0   = (float*)ws;                                   // N_NODES*HID f32
    size_t off   = (size_t)N_NODES * HID * 4;
    int*   cnt   = (int*)(ws + off);           off += (size_t)N_NODES * 4;
    int*   padded= (int*)(ws + off);           off += (size_t)N_NODES * CAP * 4;
    float* Wf0   = (float*)(ws + off);         off += HID * HID * 4;
    float* Bf0   = (float*)(ws + off);         off += HID * 4;
    float* Wf1   = (float*)(ws + off);         off += HID * HID * 4;
    float* Bf1   = (float*)(ws + off);         off += HID * 4;

    // build padded CSR (by destination)
    hipMemsetAsync(cnt, 0, (size_t)N_NODES * 4, stream);
    scatter_k<<<(N_EDGES + 255) / 256, 256, 0, stream>>>(edge_src, edge_dst, cnt, padded);

    // fused layer weights
    fusew_k<<<HID + 1, HID, 0, stream>>>(w1_0, b1_0, w2_0, b2_0, Wf0, Bf0);
    fusew_k<<<HID + 1, HID, 0, stream>>>(w1_1, b1_1, w2_1, b2_1, Wf1, Bf1);

    // x0 = embed[x_ids]  -> OUTX
    embed_k<<<(N_NODES * 32 + 255) / 256, 256, 0, stream>>>(x_ids, embed, OUTX);

    // layer 0: agg(OUTX) -> WS0 ; gemm in-place WS0
    agg_k<<<N_NODES / 4, 256, 0, stream>>>(OUTX, WS0, cnt, padded, eps0);
    gemm_k<128, true><<<(N_NODES + 63) / 64, 256, 0, stream>>>(WS0, Wf0, Bf0, WS0, N_NODES);

    // layer 1: agg(WS0) -> OUTX ; gemm in-place OUTX (final x output)
    agg_k<<<N_NODES / 4, 256, 0, stream>>>(WS0, OUTX, cnt, padded, eps1);
    gemm_k<128, true><<<(N_NODES + 63) / 64, 256, 0, stream>>>(OUTX, Wf1, Bf1, OUTX, N_NODES);

    // prediction head: y = OUTX @ wp + bp -> d_out[0 : N*OUT]
    gemm_k<64, false><<<(N_NODES + 127) / 128, 256, 0, stream>>>(OUTX, wp, bp, out, N_NODES);
}

// Round 2
// 343.817 us; speedup vs baseline: 1.8886x; 1.8886x over previous
//
#include <hip/hip_runtime.h>

typedef short short8 __attribute__((ext_vector_type(8)));
typedef float floatx4 __attribute__((ext_vector_type(4)));
typedef unsigned int uint;

#define N_NODES 100000
#define N_EDGES 1600000
#define HID 128
#define OUT_DIM 64
#define CAP 64   // max in-degree capacity (Poisson λ=16 over 100K nodes; max ~45)

// ---------- bf16 helpers (RNE) ----------
__device__ inline unsigned short f2bf(float f) {
    union { float f; uint u; } v; v.f = f;
    uint r = v.u + 0x7FFFu + ((v.u >> 16) & 1u);
    return (unsigned short)(r >> 16);
}
__device__ inline uint pack2(float a, float b) {
    return (uint)f2bf(a) | ((uint)f2bf(b) << 16);
}
__device__ inline float2 bf2f(uint u) {
    union { uint u; float f; } a, b;
    a.u = u << 16; b.u = u & 0xFFFF0000u;
    return make_float2(a.f, b.f);
}

// ---------- embed lookup -> bf16 x0 ----------
__global__ __launch_bounds__(256) void embed_k(const int* __restrict__ ids,
                                               const float* __restrict__ emb,
                                               uint* __restrict__ xb) {
    int i = blockIdx.x * 256 + threadIdx.x;
    int node = i >> 5, f = i & 31;         // 32 float4 chunks per row
    if (node < N_NODES) {
        float4 v = ((const float4*)emb)[ids[node] * 32 + f];
        uint2 p; p.x = pack2(v.x, v.y); p.y = pack2(v.z, v.w);
        ((uint2*)xb)[node * 32 + f] = p;
    }
}

// ---------- padded CSR build (by destination) ----------
__global__ __launch_bounds__(256) void scatter_k(const int* __restrict__ src,
                                                 const int* __restrict__ dst,
                                                 int* __restrict__ cnt,
                                                 int* __restrict__ padded) {
    int e = blockIdx.x * 256 + threadIdx.x;
    if (e < N_EDGES) {
        int d = dst[e];
        int pos = atomicAdd(&cnt[d], 1);
        if (pos < CAP) padded[d * CAP + pos] = src[e];
    }
}

// ---------- fused weights: Wf = w1@w2 (bf16, TRANSPOSED [col][k]), Bf = b1@w2+b2 (f32) ----------
__global__ __launch_bounds__(128) void fusew_k(const float* __restrict__ w1,
                                               const float* __restrict__ b1,
                                               const float* __restrict__ w2,
                                               const float* __restrict__ b2,
                                               unsigned short* __restrict__ WfB,
                                               float* __restrict__ Bf) {
    int j = threadIdx.x;
    int i = blockIdx.x;
    if (i < HID) {
        float s = 0.f;
        for (int k = 0; k < HID; ++k) s = fmaf(w1[i * HID + k], w2[k * HID + j], s);
        WfB[j * HID + i] = f2bf(s);     // transposed: row=output col j, k-major
    } else {
        float s = b2[j];
        for (int k = 0; k < HID; ++k) s = fmaf(b1[k], w2[k * HID + j], s);
        Bf[j] = s;
    }
}

// ---------- wp -> bf16 transposed [col][k] ----------
__global__ __launch_bounds__(256) void cvtwp_k(const float* __restrict__ wp,
                                               unsigned short* __restrict__ wpB) {
    int i = blockIdx.x * 256 + threadIdx.x;
    if (i < OUT_DIM * HID) {
        int col = i / HID, k = i % HID;
        wpB[i] = f2bf(wp[k * OUT_DIM + col]);
    }
}

// ---------- aggregation: ob[n] = bf16( (1+eps)*x[n] + sum_{e:dst=n} x[src] ), x bf16 ----------
__global__ __launch_bounds__(256) void agg_k(const uint* __restrict__ xb,
                                             uint* __restrict__ ob,
                                             const int* __restrict__ cnt,
                                             const int* __restrict__ padded,
                                             const float* __restrict__ epsp) {
    int node = blockIdx.x * 4 + (threadIdx.x >> 6);
    int lane = threadIdx.x & 63;
    int deg = cnt[node]; if (deg > CAP) deg = CAP;
    int my_src = padded[node * CAP + lane];
    float e1 = 1.0f + epsp[0];
    float2 self = bf2f(xb[node * 64 + lane]);
    float ax = self.x * e1, ay = self.y * e1;
    int j = 0;
    for (; j + 4 <= deg; j += 4) {   // unroll-4: 4 loads in flight
        int s0 = __shfl(my_src, j),     s1 = __shfl(my_src, j + 1);
        int s2 = __shfl(my_src, j + 2), s3 = __shfl(my_src, j + 3);
        uint u0 = xb[s0 * 64 + lane], u1 = xb[s1 * 64 + lane];
        uint u2 = xb[s2 * 64 + lane], u3 = xb[s3 * 64 + lane];
        float2 v0 = bf2f(u0), v1 = bf2f(u1), v2 = bf2f(u2), v3 = bf2f(u3);
        ax += (v0.x + v1.x) + (v2.x + v3.x);
        ay += (v0.y + v1.y) + (v2.y + v3.y);
    }
    for (; j < deg; ++j) {
        int s = __shfl(my_src, j);
        float2 v = bf2f(xb[s * 64 + lane]);
        ax += v.x; ay += v.y;
    }
    ob[node * 64 + lane] = pack2(ax, ay);
}

// ---------- MFMA GEMM: Out = [relu](A @ W^T' + bias) ----------
// A: [M][HID] (bf16 or f32), Wt: [NC][HID] bf16 (k-major), Out: [M][NC]
template <int NC, bool RELU, bool A_F32, bool OUT_BF16>
__global__ __launch_bounds__(256) void mgemm_k(const void* __restrict__ Ain,
                                               const unsigned short* __restrict__ Wt,
                                               const float* __restrict__ bias,
                                               void* __restrict__ Out, int M) {
    constexpr int LDK = HID + 8;                 // padded k-stride (bf16 elems)
    __shared__ unsigned short As[64 * LDK];      // 17.4 KB
    __shared__ unsigned short Ws[NC * LDK];      // 34.8 KB (NC=128)
    int tid = threadIdx.x;
    int row0 = blockIdx.x * 64;

    // stage W (16B chunks of 8 bf16)
    for (int c = tid; c < NC * 16; c += 256) {
        int r = c >> 4, cc = c & 15;
        uint4 v = ((const uint4*)Wt)[c];
        *(uint4*)&Ws[r * LDK + cc * 8] = v;
    }
    // stage A tile (convert to bf16 if fp32 source)
    if (A_F32) {
        const float4* A4 = (const float4*)Ain;
        for (int c = tid; c < 64 * 16; c += 256) {
            int r = c >> 4, cc = c & 15;
            int gr = row0 + r;
            float4 a = make_float4(0.f,0.f,0.f,0.f), b = a;
            if (gr < M) { a = A4[(long)gr * 32 + cc * 2]; b = A4[(long)gr * 32 + cc * 2 + 1]; }
            uint4 p;
            p.x = pack2(a.x, a.y); p.y = pack2(a.z, a.w);
            p.z = pack2(b.x, b.y); p.w = pack2(b.z, b.w);
            *(uint4*)&As[r * LDK + cc * 8] = p;
        }
    } else {
        const uint4* A4 = (const uint4*)Ain;
        for (int c = tid; c < 64 * 16; c += 256) {
            int r = c >> 4, cc = c & 15;
            int gr = row0 + r;
            uint4 v = make_uint4(0u,0u,0u,0u);
            if (gr < M) v = A4[(long)gr * 16 + cc];
            *(uint4*)&As[r * LDK + cc * 8] = v;
        }
    }
    __syncthreads();

    int wid = tid >> 6, lane = tid & 63;
    int lrow = lane & 15, lk = (lane >> 4) * 8;

    short8 af[4];
#pragma unroll
    for (int k = 0; k < 4; ++k)
        af[k] = *(const short8*)&As[(wid * 16 + lrow) * LDK + k * 32 + lk];

    constexpr int NT = NC / 16;
    floatx4 acc[NT];
#pragma unroll
    for (int n = 0; n < NT; ++n) acc[n] = (floatx4){0.f, 0.f, 0.f, 0.f};

#pragma unroll
    for (int n = 0; n < NT; ++n) {
#pragma unroll
        for (int k = 0; k < 4; ++k) {
            short8 bfr = *(const short8*)&Ws[(n * 16 + lrow) * LDK + k * 32 + lk];
            acc[n] = __builtin_amdgcn_mfma_f32_16x16x32_bf16(af[k], bfr, acc[n], 0, 0, 0);
        }
    }

    // D: col = lane&15, row = (lane>>4)*4 + reg
    int orow = row0 + wid * 16 + (lane >> 4) * 4;
#pragma unroll
    for (int n = 0; n < NT; ++n) {
        int col = n * 16 + lrow;
        float bv = bias[col];
#pragma unroll
        for (int r = 0; r < 4; ++r) {
            int gr = orow + r;
            if (gr < M) {
                float v = acc[n][r] + bv;
                if (RELU && v < 0.f) v = 0.f;
                if (OUT_BF16) ((unsigned short*)Out)[(long)gr * NC + col] = f2bf(v);
                else          ((float*)Out)[(long)gr * NC + col] = v;
            }
        }
    }
}

extern "C" void kernel_launch(void* const* d_in, const int* in_sizes, int n_in,
                              void* d_out, int out_size, void* d_ws, size_t ws_size,
                              hipStream_t stream) {
    const int*   x_ids    = (const int*)d_in[0];
    const int*   edge_src = (const int*)d_in[1];
    const int*   edge_dst = (const int*)d_in[2];
    const float* embed    = (const float*)d_in[3];
    const float* eps0     = (const float*)d_in[4];
    const float* w1_0     = (const float*)d_in[5];
    const float* b1_0     = (const float*)d_in[6];
    const float* w2_0     = (const float*)d_in[7];
    const float* b2_0     = (const float*)d_in[8];
    const float* eps1     = (const float*)d_in[9];
    const float* w1_1     = (const float*)d_in[10];
    const float* b1_1     = (const float*)d_in[11];
    const float* w2_1     = (const float*)d_in[12];
    const float* b2_1     = (const float*)d_in[13];
    const float* wp       = (const float*)d_in[14];
    const float* bp       = (const float*)d_in[15];

    float* out  = (float*)d_out;                            // y region: N*64 f32 (25.6 MB)
    float* OUTX = out + (size_t)N_NODES * OUT_DIM;          // x region: N*128 f32 (final output)
    uint*  XB   = (uint*)out;  // y region doubles as bf16 feature buffer [N][64] uints (exact fit)

    char* ws = (char*)d_ws;
    size_t off = 0;
    uint* AGG = (uint*)(ws + off);              off += (size_t)N_NODES * 64 * 4;   // bf16 agg
    int*  padded = (int*)(ws + off);            off += (size_t)N_NODES * CAP * 4;
    int*  cnt = (int*)(ws + off);               off += (size_t)N_NODES * 4;
    unsigned short* WfB0 = (unsigned short*)(ws + off); off += HID * HID * 2;
    unsigned short* WfB1 = (unsigned short*)(ws + off); off += HID * HID * 2;
    unsigned short* wpB  = (unsigned short*)(ws + off); off += OUT_DIM * HID * 2;
    float* Bf0 = (float*)(ws + off);            off += HID * 4;
    float* Bf1 = (float*)(ws + off);            off += HID * 4;

    hipMemsetAsync(cnt, 0, (size_t)N_NODES * 4, stream);
    scatter_k<<<(N_EDGES + 255) / 256, 256, 0, stream>>>(edge_src, edge_dst, cnt, padded);

    fusew_k<<<HID + 1, HID, 0, stream>>>(w1_0, b1_0, w2_0, b2_0, WfB0, Bf0);
    fusew_k<<<HID + 1, HID, 0, stream>>>(w1_1, b1_1, w2_1, b2_1, WfB1, Bf1);
    cvtwp_k<<<(OUT_DIM * HID + 255) / 256, 256, 0, stream>>>(wp, wpB);

    // x0 (bf16) -> XB (y region)
    embed_k<<<(N_NODES * 32 + 255) / 256, 256, 0, stream>>>(x_ids, embed, XB);

    const int GB = (N_NODES + 63) / 64;
    // layer 0
    agg_k<<<N_NODES / 4, 256, 0, stream>>>(XB, AGG, cnt, padded, eps0);
    mgemm_k<HID, true, false, true><<<GB, 256, 0, stream>>>(AGG, WfB0, Bf0, XB, N_NODES);
    // layer 1
    agg_k<<<N_NODES / 4, 256, 0, stream>>>(XB, AGG, cnt, padded, eps1);
    mgemm_k<HID, true, false, false><<<GB, 256, 0, stream>>>(AGG, WfB1, Bf1, OUTX, N_NODES);
    // prediction head (reads fp32 x, writes y over the bf16 buffer — consumed by then)
    mgemm_k<OUT_DIM, false, true, false><<<GB, 256, 0, stream>>>(OUTX, wpB, bp, out, N_NODES);
}

// Round 3
// 265.834 us; speedup vs baseline: 2.4426x; 1.2934x over previous
//
#include <hip/hip_runtime.h>

typedef short short8 __attribute__((ext_vector_type(8)));
typedef float floatx4 __attribute__((ext_vector_type(4)));
typedef unsigned int uint;

#define N_NODES 100000
#define N_EDGES 1600000
#define HID 128
#define OUT_DIM 64
#define NBUCK 196      // ceil(100000 / 512) buckets of 512 dst nodes
#define CAPB 10240     // per-bucket capacity (mean 8163, sigma ~90 -> 23 sigma margin)
#define EPB 2048       // edges per block in bucket_k

// ---------- bf16 helpers (RNE) ----------
__device__ inline unsigned short f2bf(float f) {
    union { float f; uint u; } v; v.f = f;
    uint r = v.u + 0x7FFFu + ((v.u >> 16) & 1u);
    return (unsigned short)(r >> 16);
}
__device__ inline uint pack2(float a, float b) {
    return (uint)f2bf(a) | ((uint)f2bf(b) << 16);
}
__device__ inline float2 bf2f(uint u) {
    union { uint u; float f; } a, b;
    a.u = u << 16; b.u = u & 0xFFFF0000u;
    return make_float2(a.f, b.f);
}

// ---------- embed lookup -> bf16 x0 ----------
__global__ __launch_bounds__(256) void embed_k(const int* __restrict__ ids,
                                               const float* __restrict__ emb,
                                               uint* __restrict__ xb) {
    int i = blockIdx.x * 256 + threadIdx.x;
    int node = i >> 5, f = i & 31;
    if (node < N_NODES) {
        float4 v = ((const float4*)emb)[ids[node] * 32 + f];
        uint2 p; p.x = pack2(v.x, v.y); p.y = pack2(v.z, v.w);
        ((uint2*)xb)[node * 32 + f] = p;
    }
}

// ---------- pass A: bucket edges by dst>>9, tail-append runs ----------
__global__ __launch_bounds__(256) void bucket_k(const int* __restrict__ src,
                                                const int* __restrict__ dst,
                                                int* __restrict__ tails,
                                                uint* __restrict__ pairs) {
    __shared__ int lcnt[NBUCK];
    __shared__ int lbase[NBUCK];
    int tid = threadIdx.x;
    for (int i = tid; i < NBUCK; i += 256) lcnt[i] = 0;
    __syncthreads();
    int e0 = blockIdx.x * EPB;
    int b[8], p[8]; uint val[8];
#pragma unroll
    for (int k = 0; k < 8; ++k) {
        int e = e0 + k * 256 + tid;
        if (e < N_EDGES) {
            int d = dst[e], s = src[e];
            b[k] = d >> 9;
            val[k] = (uint)s | ((uint)(d & 511) << 17);
            p[k] = atomicAdd(&lcnt[b[k]], 1);
        } else b[k] = -1;
    }
    __syncthreads();
    for (int i = tid; i < NBUCK; i += 256)
        lbase[i] = (lcnt[i] > 0) ? atomicAdd(&tails[i], lcnt[i]) : 0;
    __syncthreads();
#pragma unroll
    for (int k = 0; k < 8; ++k) {
        if (b[k] >= 0) {
            int pos = lbase[b[k]] + p[k];
            if (pos < CAPB) pairs[b[k] * CAPB + pos] = val[k];
        }
    }
}

// ---------- pass B: per-bucket counting sort -> exact CSR ----------
__global__ __launch_bounds__(256) void binsort_k(const int* __restrict__ tails,
                                                 const uint* __restrict__ pairs,
                                                 uint* __restrict__ csr,
                                                 int* __restrict__ row_start,
                                                 int* __restrict__ row_cnt) {
    int b = blockIdx.x;
    int d0 = b << 9;
    int ne = tails[b]; if (ne > CAPB) ne = CAPB;
    __shared__ int cnt[512];
    __shared__ int pre[512];
    int tid = threadIdx.x;
    cnt[tid] = 0; cnt[tid + 256] = 0;
    __syncthreads();
    for (int i = tid; i < ne; i += 256)
        atomicAdd(&cnt[pairs[b * CAPB + i] >> 17], 1);
    __syncthreads();
    if (tid < 64) {           // exclusive prefix of 512 counters: 8/lane + wave scan
        int base = tid * 8;
        int loc[8]; int s = 0;
#pragma unroll
        for (int k = 0; k < 8; ++k) { loc[k] = s; s += cnt[base + k]; }
        int excl = s;
        for (int off = 1; off < 64; off <<= 1) {
            int v = __shfl_up(excl, off);
            if (tid >= off) excl += v;
        }
        excl -= s;            // exclusive
#pragma unroll
        for (int k = 0; k < 8; ++k) pre[base + k] = excl + loc[k];
    }
    __syncthreads();
    int gbase = b * CAPB;
    for (int i = tid; i < 512; i += 256) {
        int d = d0 + i;
        if (d < N_NODES) { row_start[d] = gbase + pre[i]; row_cnt[d] = cnt[i]; }
    }
    __syncthreads();
    for (int i = tid; i < ne; i += 256) {
        uint u = pairs[b * CAPB + i];
        int pos = atomicAdd(&pre[u >> 17], 1);
        csr[gbase + pos] = u & 0x1FFFFu;
    }
}

// ---------- fused weights ----------
__global__ __launch_bounds__(128) void fusew_k(const float* __restrict__ w1,
                                               const float* __restrict__ b1,
                                               const float* __restrict__ w2,
                                               const float* __restrict__ b2,
                                               unsigned short* __restrict__ WfB,
                                               float* __restrict__ Bf) {
    int j = threadIdx.x;
    int i = blockIdx.x;
    if (i < HID) {
        float s = 0.f;
        for (int k = 0; k < HID; ++k) s = fmaf(w1[i * HID + k], w2[k * HID + j], s);
        WfB[j * HID + i] = f2bf(s);
    } else {
        float s = b2[j];
        for (int k = 0; k < HID; ++k) s = fmaf(b1[k], w2[k * HID + j], s);
        Bf[j] = s;
    }
}

__global__ __launch_bounds__(256) void cvtwp_k(const float* __restrict__ wp,
                                               unsigned short* __restrict__ wpB) {
    int i = blockIdx.x * 256 + threadIdx.x;
    if (i < OUT_DIM * HID) {
        int col = i / HID, k = i % HID;
        wpB[i] = f2bf(wp[k * OUT_DIM + col]);
    }
}

// ---------- aggregation via CSR ----------
__global__ __launch_bounds__(256) void agg_k(const uint* __restrict__ xb,
                                             uint* __restrict__ ob,
                                             const int* __restrict__ row_start,
                                             const int* __restrict__ row_cnt,
                                             const uint* __restrict__ csr,
                                             const float* __restrict__ epsp) {
    int node = blockIdx.x * 4 + (threadIdx.x >> 6);
    int lane = threadIdx.x & 63;
    int start = row_start[node];
    int deg = row_cnt[node];
    float e1 = 1.0f + epsp[0];
    float2 self = bf2f(xb[node * 64 + lane]);
    float ax = self.x * e1, ay = self.y * e1;
    for (int base = 0; base < deg; base += 64) {
        int m = deg - base; if (m > 64) m = 64;
        int my = (lane < m) ? (int)csr[start + base + lane] : 0;
        int j = 0;
        for (; j + 4 <= m; j += 4) {
            int s0 = __shfl(my, j),     s1 = __shfl(my, j + 1);
            int s2 = __shfl(my, j + 2), s3 = __shfl(my, j + 3);
            uint u0 = xb[s0 * 64 + lane], u1 = xb[s1 * 64 + lane];
            uint u2 = xb[s2 * 64 + lane], u3 = xb[s3 * 64 + lane];
            float2 v0 = bf2f(u0), v1 = bf2f(u1), v2 = bf2f(u2), v3 = bf2f(u3);
            ax += (v0.x + v1.x) + (v2.x + v3.x);
            ay += (v0.y + v1.y) + (v2.y + v3.y);
        }
        for (; j < m; ++j) {
            int s = __shfl(my, j);
            float2 v = bf2f(xb[s * 64 + lane]);
            ax += v.x; ay += v.y;
        }
    }
    ob[node * 64 + lane] = pack2(ax, ay);
}

// ---------- MFMA GEMM: Out = relu(A @ Wt' + bias); optional fused head ----------
// A: [M][HID] bf16, Wt: [NC][HID] bf16 k-major. If FUSE: also y = X @ wpt' + bp.
template <int NC, bool OUT_BF16, bool FUSE>
__global__ __launch_bounds__(256) void mgemm_k(const uint* __restrict__ Ain,
                                               const unsigned short* __restrict__ Wt,
                                               const float* __restrict__ bias,
                                               void* __restrict__ Out, int M,
                                               const unsigned short* __restrict__ wpt,
                                               const float* __restrict__ bp,
                                               float* __restrict__ yout) {
    constexpr int LDK = HID + 8;
    __shared__ unsigned short As[64 * LDK];
    __shared__ unsigned short Ws[NC * LDK];
    int tid = threadIdx.x;
    int row0 = blockIdx.x * 64;

    for (int c = tid; c < NC * 16; c += 256) {
        int r = c >> 4, cc = c & 15;
        uint4 v = ((const uint4*)Wt)[c];
        *(uint4*)&Ws[r * LDK + cc * 8] = v;
    }
    const uint4* A4 = (const uint4*)Ain;
    for (int c = tid; c < 64 * 16; c += 256) {
        int r = c >> 4, cc = c & 15;
        int gr = row0 + r;
        uint4 v = make_uint4(0u, 0u, 0u, 0u);
        if (gr < M) v = A4[(long)gr * 16 + cc];
        *(uint4*)&As[r * LDK + cc * 8] = v;
    }
    __syncthreads();

    int wid = tid >> 6, lane = tid & 63;
    int lrow = lane & 15, lk = (lane >> 4) * 8;

    short8 af[4];
#pragma unroll
    for (int k = 0; k < 4; ++k)
        af[k] = *(const short8*)&As[(wid * 16 + lrow) * LDK + k * 32 + lk];

    constexpr int NT = NC / 16;
    floatx4 acc[NT];
#pragma unroll
    for (int n = 0; n < NT; ++n) acc[n] = (floatx4){0.f, 0.f, 0.f, 0.f};
#pragma unroll
    for (int n = 0; n < NT; ++n)
#pragma unroll
        for (int k = 0; k < 4; ++k) {
            short8 bfr = *(const short8*)&Ws[(n * 16 + lrow) * LDK + k * 32 + lk];
            acc[n] = __builtin_amdgcn_mfma_f32_16x16x32_bf16(af[k], bfr, acc[n], 0, 0, 0);
        }

    if (FUSE) __syncthreads();   // As/Ws reads done; about to overwrite

    int orow = row0 + wid * 16 + (lane >> 4) * 4;
    int lrowbase = wid * 16 + (lane >> 4) * 4;
#pragma unroll
    for (int n = 0; n < NT; ++n) {
        int col = n * 16 + lrow;
        float bv = bias[col];
#pragma unroll
        for (int r = 0; r < 4; ++r) {
            int gr = orow + r;
            float v = acc[n][r] + bv;
            if (v < 0.f) v = 0.f;            // relu (all non-head layers)
            if (gr < M) {
                if (OUT_BF16) ((unsigned short*)Out)[(long)gr * NC + col] = f2bf(v);
                else          ((float*)Out)[(long)gr * NC + col] = v;
            }
            if (FUSE) As[(lrowbase + r) * LDK + col] = f2bf(v);
        }
    }

    if (FUSE) {
        // restage head weights wpt [64][HID] into Ws
        for (int c = tid; c < 64 * 16; c += 256) {
            int r = c >> 4, cc = c & 15;
            uint4 v = ((const uint4*)wpt)[c];
            *(uint4*)&Ws[r * LDK + cc * 8] = v;
        }
        __syncthreads();
        short8 af2[4];
#pragma unroll
        for (int k = 0; k < 4; ++k)
            af2[k] = *(const short8*)&As[(wid * 16 + lrow) * LDK + k * 32 + lk];
        floatx4 acc2[4];
#pragma unroll
        for (int n = 0; n < 4; ++n) acc2[n] = (floatx4){0.f, 0.f, 0.f, 0.f};
#pragma unroll
        for (int n = 0; n < 4; ++n)
#pragma unroll
            for (int k = 0; k < 4; ++k) {
                short8 bfr = *(const short8*)&Ws[(n * 16 + lrow) * LDK + k * 32 + lk];
                acc2[n] = __builtin_amdgcn_mfma_f32_16x16x32_bf16(af2[k], bfr, acc2[n], 0, 0, 0);
            }
#pragma unroll
        for (int n = 0; n < 4; ++n) {
            int col = n * 16 + lrow;
            float bv = bp[col];
#pragma unroll
            for (int r = 0; r < 4; ++r) {
                int gr = orow + r;
                if (gr < M) yout[(long)gr * OUT_DIM + col] = acc2[n][r] + bv;
            }
        }
    }
}

extern "C" void kernel_launch(void* const* d_in, const int* in_sizes, int n_in,
                              void* d_out, int out_size, void* d_ws, size_t ws_size,
                              hipStream_t stream) {
    const int*   x_ids    = (const int*)d_in[0];
    const int*   edge_src = (const int*)d_in[1];
    const int*   edge_dst = (const int*)d_in[2];
    const float* embed    = (const float*)d_in[3];
    const float* eps0     = (const float*)d_in[4];
    const float* w1_0     = (const float*)d_in[5];
    const float* b1_0     = (const float*)d_in[6];
    const float* w2_0     = (const float*)d_in[7];
    const float* b2_0     = (const float*)d_in[8];
    const float* eps1     = (const float*)d_in[9];
    const float* w1_1     = (const float*)d_in[10];
    const float* b1_1     = (const float*)d_in[11];
    const float* w2_1     = (const float*)d_in[12];
    const float* b2_1     = (const float*)d_in[13];
    const float* wp       = (const float*)d_in[14];
    const float* bp       = (const float*)d_in[15];

    float* out  = (float*)d_out;
    float* OUTX = out + (size_t)N_NODES * OUT_DIM;
    uint*  XB   = (uint*)out;   // y region doubles as bf16 feature buffer until the end

    char* ws = (char*)d_ws;
    size_t off = 0;
    uint* AGG  = (uint*)(ws + off);             off += (size_t)N_NODES * 64 * 4;
    uint* pairs= (uint*)(ws + off);             off += (size_t)NBUCK * CAPB * 4;
    uint* csr  = (uint*)(ws + off);             off += (size_t)NBUCK * CAPB * 4;
    int* row_start = (int*)(ws + off);          off += (size_t)N_NODES * 4;
    int* row_cnt   = (int*)(ws + off);          off += (size_t)N_NODES * 4;
    unsigned short* WfB0 = (unsigned short*)(ws + off); off += HID * HID * 2;
    unsigned short* WfB1 = (unsigned short*)(ws + off); off += HID * HID * 2;
    unsigned short* wpB  = (unsigned short*)(ws + off); off += OUT_DIM * HID * 2;
    float* Bf0 = (float*)(ws + off);            off += HID * 4;
    float* Bf1 = (float*)(ws + off);            off += HID * 4;
    int* tails = (int*)(ws + off);              off += NBUCK * 4;

    hipMemsetAsync(tails, 0, NBUCK * 4, stream);
    bucket_k<<<(N_EDGES + EPB - 1) / EPB, 256, 0, stream>>>(edge_src, edge_dst, tails, pairs);
    binsort_k<<<NBUCK, 256, 0, stream>>>(tails, pairs, csr, row_start, row_cnt);

    fusew_k<<<HID + 1, HID, 0, stream>>>(w1_0, b1_0, w2_0, b2_0, WfB0, Bf0);
    fusew_k<<<HID + 1, HID, 0, stream>>>(w1_1, b1_1, w2_1, b2_1, WfB1, Bf1);
    cvtwp_k<<<(OUT_DIM * HID + 255) / 256, 256, 0, stream>>>(wp, wpB);

    embed_k<<<(N_NODES * 32 + 255) / 256, 256, 0, stream>>>(x_ids, embed, XB);

    const int GB = (N_NODES + 63) / 64;
    // layer 0
    agg_k<<<N_NODES / 4, 256, 0, stream>>>(XB, AGG, row_start, row_cnt, csr, eps0);
    mgemm_k<HID, true, false><<<GB, 256, 0, stream>>>(AGG, WfB0, Bf0, XB, N_NODES,
                                                      nullptr, nullptr, nullptr);
    // layer 1 + fused prediction head
    agg_k<<<N_NODES / 4, 256, 0, stream>>>(XB, AGG, row_start, row_cnt, csr, eps1);
    mgemm_k<HID, false, true><<<GB, 256, 0, stream>>>(AGG, WfB1, Bf1, OUTX, N_NODES,
                                                      wpB, bp, out);
}

// Round 4
// 250.374 us; speedup vs baseline: 2.5934x; 1.0617x over previous
//
#include <hip/hip_runtime.h>

typedef short short8 __attribute__((ext_vector_type(8)));
typedef float floatx4 __attribute__((ext_vector_type(4)));
typedef unsigned int uint;

#define N_NODES 100000
#define N_EDGES 1600000
#define HID 128
#define OUT_DIM 64
#define VOCAB 28
#define NBUCK 196      // ceil(100000 / 512) buckets of 512 dst nodes
#define CAPB 10240     // per-bucket capacity (mean 8163, sigma ~90)
#define EPB 2048       // edges per block in bucket_k

// csr entry packing: bits[0:16]=src, bits[17:21]=vocab id of src
// pairs entry packing: bits[0:16]=src, bits[17:25]=dst&511, bits[26:30]=vocab id

// ---------- bf16 helpers (RNE) ----------
__device__ inline unsigned short f2bf(float f) {
    union { float f; uint u; } v; v.f = f;
    uint r = v.u + 0x7FFFu + ((v.u >> 16) & 1u);
    return (unsigned short)(r >> 16);
}
__device__ inline uint pack2(float a, float b) {
    return (uint)f2bf(a) | ((uint)f2bf(b) << 16);
}
__device__ inline float2 bf2f(uint u) {
    union { uint u; float f; } a, b;
    a.u = u << 16; b.u = u & 0xFFFF0000u;
    return make_float2(a.f, b.f);
}

// ---------- pass A: bucket edges by dst>>9, tail-append runs ----------
__global__ __launch_bounds__(256) void bucket_k(const int* __restrict__ src,
                                                const int* __restrict__ dst,
                                                const int* __restrict__ ids,
                                                int* __restrict__ tails,
                                                uint* __restrict__ pairs) {
    __shared__ int lcnt[NBUCK];
    __shared__ int lbase[NBUCK];
    int tid = threadIdx.x;
    for (int i = tid; i < NBUCK; i += 256) lcnt[i] = 0;
    __syncthreads();
    int e0 = blockIdx.x * EPB;
    int b[8], p[8]; uint val[8];
#pragma unroll
    for (int k = 0; k < 8; ++k) {
        int e = e0 + k * 256 + tid;
        if (e < N_EDGES) {
            int d = dst[e], s = src[e];
            uint vid = (uint)ids[s];
            b[k] = d >> 9;
            val[k] = (uint)s | ((uint)(d & 511) << 17) | (vid << 26);
            p[k] = atomicAdd(&lcnt[b[k]], 1);
        } else b[k] = -1;
    }
    __syncthreads();
    for (int i = tid; i < NBUCK; i += 256)
        lbase[i] = (lcnt[i] > 0) ? atomicAdd(&tails[i], lcnt[i]) : 0;
    __syncthreads();
#pragma unroll
    for (int k = 0; k < 8; ++k) {
        if (b[k] >= 0) {
            int pos = lbase[b[k]] + p[k];
            if (pos < CAPB) pairs[b[k] * CAPB + pos] = val[k];
        }
    }
}

// ---------- pass B: per-bucket counting sort -> exact CSR ----------
__global__ __launch_bounds__(256) void binsort_k(const int* __restrict__ tails,
                                                 const uint* __restrict__ pairs,
                                                 uint* __restrict__ csr,
                                                 int* __restrict__ row_start,
                                                 int* __restrict__ row_cnt) {
    int b = blockIdx.x;
    int d0 = b << 9;
    int ne = tails[b]; if (ne > CAPB) ne = CAPB;
    __shared__ int cnt[512];
    __shared__ int pre[512];
    int tid = threadIdx.x;
    cnt[tid] = 0; cnt[tid + 256] = 0;
    __syncthreads();
    for (int i = tid; i < ne; i += 256)
        atomicAdd(&cnt[(pairs[b * CAPB + i] >> 17) & 511u], 1);
    __syncthreads();
    if (tid < 64) {
        int base = tid * 8;
        int loc[8]; int s = 0;
#pragma unroll
        for (int k = 0; k < 8; ++k) { loc[k] = s; s += cnt[base + k]; }
        int excl = s;
        for (int off = 1; off < 64; off <<= 1) {
            int v = __shfl_up(excl, off);
            if (tid >= off) excl += v;
        }
        excl -= s;
#pragma unroll
        for (int k = 0; k < 8; ++k) pre[base + k] = excl + loc[k];
    }
    __syncthreads();
    int gbase = b * CAPB;
    for (int i = tid; i < 512; i += 256) {
        int d = d0 + i;
        if (d < N_NODES) { row_start[d] = gbase + pre[i]; row_cnt[d] = cnt[i]; }
    }
    __syncthreads();
    for (int i = tid; i < ne; i += 256) {
        uint u = pairs[b * CAPB + i];
        int pos = atomicAdd(&pre[(u >> 17) & 511u], 1);
        csr[gbase + pos] = (u & 0x1FFFFu) | ((u >> 26) << 17);
    }
}

// ---------- fused weights ----------
__global__ __launch_bounds__(128) void fusew_k(const float* __restrict__ w1,
                                               const float* __restrict__ b1,
                                               const float* __restrict__ w2,
                                               const float* __restrict__ b2,
                                               unsigned short* __restrict__ WfB,
                                               float* __restrict__ Bf) {
    int j = threadIdx.x;
    int i = blockIdx.x;
    if (i < HID) {
        float s = 0.f;
        for (int k = 0; k < HID; ++k) s = fmaf(w1[i * HID + k], w2[k * HID + j], s);
        WfB[j * HID + i] = f2bf(s);
    } else {
        float s = b2[j];
        for (int k = 0; k < HID; ++k) s = fmaf(b1[k], w2[k * HID + j], s);
        Bf[j] = s;
    }
}

__global__ __launch_bounds__(256) void cvtwp_k(const float* __restrict__ wp,
                                               unsigned short* __restrict__ wpB) {
    int i = blockIdx.x * 256 + threadIdx.x;
    if (i < OUT_DIM * HID) {
        int col = i / HID, k = i % HID;
        wpB[i] = f2bf(wp[k * OUT_DIM + col]);
    }
}

// ---------- layer 0 fully fused: LDS-embed aggregation + MFMA GEMM ----------
// out = bf16( relu( agg0 @ Wt' + bias ) ),  agg from embed table (LDS-resident)
__global__ __launch_bounds__(256) void gin0_k(const int* __restrict__ ids,
                                              const float* __restrict__ embf,
                                              const int* __restrict__ row_start,
                                              const int* __restrict__ row_cnt,
                                              const uint* __restrict__ csr,
                                              const float* __restrict__ epsp,
                                              const unsigned short* __restrict__ Wt,
                                              const float* __restrict__ bias,
                                              unsigned short* __restrict__ OutB, int M) {
    constexpr int LDK = HID + 8;                  // bf16 elems; /2 = 68 uints
    __shared__ uint embs[VOCAB * 64];             // 7 KB bf16 embed table
    __shared__ unsigned short As[64 * LDK];       // 17.4 KB
    int tid = threadIdx.x;
    int row0 = blockIdx.x * 64;
    int wid = tid >> 6, lane = tid & 63;

    for (int i = tid; i < VOCAB * 64; i += 256) {
        float2 v = ((const float2*)embf)[i];
        embs[i] = pack2(v.x, v.y);
    }
    __syncthreads();

    float e1 = 1.0f + epsp[0];
    for (int n16 = 0; n16 < 16; ++n16) {
        int lr = wid * 16 + n16;
        int node = row0 + lr;
        float ax = 0.f, ay = 0.f;
        if (node < M) {
            int sid = ids[node];
            float2 sv = bf2f(embs[sid * 64 + lane]);
            ax = sv.x * e1; ay = sv.y * e1;
            int start = row_start[node];
            int deg = row_cnt[node];
            for (int base = 0; base < deg; base += 64) {
                int m = deg - base; if (m > 64) m = 64;
                uint my = (lane < m) ? csr[start + base + lane] : 0u;
                int j = 0;
                for (; j + 4 <= m; j += 4) {
                    uint v0 = __shfl(my, j),     v1 = __shfl(my, j + 1);
                    uint v2 = __shfl(my, j + 2), v3 = __shfl(my, j + 3);
                    float2 f0 = bf2f(embs[(v0 >> 17) * 64 + lane]);
                    float2 f1 = bf2f(embs[(v1 >> 17) * 64 + lane]);
                    float2 f2 = bf2f(embs[(v2 >> 17) * 64 + lane]);
                    float2 f3 = bf2f(embs[(v3 >> 17) * 64 + lane]);
                    ax += (f0.x + f1.x) + (f2.x + f3.x);
                    ay += (f0.y + f1.y) + (f2.y + f3.y);
                }
                for (; j < m; ++j) {
                    uint v = __shfl(my, j);
                    float2 f = bf2f(embs[(v >> 17) * 64 + lane]);
                    ax += f.x; ay += f.y;
                }
            }
        }
        ((uint*)As)[lr * (LDK / 2) + lane] = pack2(ax, ay);
    }
    __syncthreads();

    int lrow = lane & 15, lk = (lane >> 4) * 8;
    short8 af[4];
#pragma unroll
    for (int k = 0; k < 4; ++k)
        af[k] = *(const short8*)&As[(wid * 16 + lrow) * LDK + k * 32 + lk];

    floatx4 acc[8];
#pragma unroll
    for (int n = 0; n < 8; ++n) acc[n] = (floatx4){0.f, 0.f, 0.f, 0.f};
#pragma unroll
    for (int n = 0; n < 8; ++n)
#pragma unroll
        for (int k = 0; k < 4; ++k) {
            // W is 32 KB, read identically by all blocks -> L1/L2-resident
            short8 bfr = *(const short8*)&Wt[(n * 16 + lrow) * HID + k * 32 + lk];
            acc[n] = __builtin_amdgcn_mfma_f32_16x16x32_bf16(af[k], bfr, acc[n], 0, 0, 0);
        }

    int orow = row0 + wid * 16 + (lane >> 4) * 4;
#pragma unroll
    for (int n = 0; n < 8; ++n) {
        int col = n * 16 + lrow;
        float bv = bias[col];
#pragma unroll
        for (int r = 0; r < 4; ++r) {
            int gr = orow + r;
            if (gr < M) {
                float v = acc[n][r] + bv;
                if (v < 0.f) v = 0.f;
                OutB[(long)gr * HID + col] = f2bf(v);
            }
        }
    }
}

// ---------- layer-1 aggregation via CSR (global gather from bf16 XB) ----------
__global__ __launch_bounds__(256) void agg_k(const uint* __restrict__ xb,
                                             uint* __restrict__ ob,
                                             const int* __restrict__ row_start,
                                             const int* __restrict__ row_cnt,
                                             const uint* __restrict__ csr,
                                             const float* __restrict__ epsp) {
    int node = blockIdx.x * 4 + (threadIdx.x >> 6);
    int lane = threadIdx.x & 63;
    int start = row_start[node];
    int deg = row_cnt[node];
    float e1 = 1.0f + epsp[0];
    float2 self = bf2f(xb[node * 64 + lane]);
    float ax = self.x * e1, ay = self.y * e1;
    for (int base = 0; base < deg; base += 64) {
        int m = deg - base; if (m > 64) m = 64;
        int my = (lane < m) ? (int)(csr[start + base + lane] & 0x1FFFFu) : 0;
        int j = 0;
        for (; j + 4 <= m; j += 4) {
            int s0 = __shfl(my, j),     s1 = __shfl(my, j + 1);
            int s2 = __shfl(my, j + 2), s3 = __shfl(my, j + 3);
            uint u0 = xb[s0 * 64 + lane], u1 = xb[s1 * 64 + lane];
            uint u2 = xb[s2 * 64 + lane], u3 = xb[s3 * 64 + lane];
            float2 v0 = bf2f(u0), v1 = bf2f(u1), v2 = bf2f(u2), v3 = bf2f(u3);
            ax += (v0.x + v1.x) + (v2.x + v3.x);
            ay += (v0.y + v1.y) + (v2.y + v3.y);
        }
        for (; j < m; ++j) {
            int s = __shfl(my, j);
            float2 v = bf2f(xb[s * 64 + lane]);
            ax += v.x; ay += v.y;
        }
    }
    ob[node * 64 + lane] = pack2(ax, ay);
}

// ---------- layer-1 MFMA GEMM + fused prediction head ----------
__global__ __launch_bounds__(256) void mgemm1_k(const uint* __restrict__ Ain,
                                                const unsigned short* __restrict__ Wt,
                                                const float* __restrict__ bias,
                                                float* __restrict__ Out, int M,
                                                const unsigned short* __restrict__ wpt,
                                                const float* __restrict__ bp,
                                                float* __restrict__ yout) {
    constexpr int LDK = HID + 8;
    __shared__ unsigned short As[64 * LDK];
    __shared__ unsigned short Ws[HID * LDK];
    int tid = threadIdx.x;
    int row0 = blockIdx.x * 64;

    for (int c = tid; c < HID * 16; c += 256) {
        int r = c >> 4, cc = c & 15;
        uint4 v = ((const uint4*)Wt)[c];
        *(uint4*)&Ws[r * LDK + cc * 8] = v;
    }
    const uint4* A4 = (const uint4*)Ain;
    for (int c = tid; c < 64 * 16; c += 256) {
        int r = c >> 4, cc = c & 15;
        int gr = row0 + r;
        uint4 v = make_uint4(0u, 0u, 0u, 0u);
        if (gr < M) v = A4[(long)gr * 16 + cc];
        *(uint4*)&As[r * LDK + cc * 8] = v;
    }
    __syncthreads();

    int wid = tid >> 6, lane = tid & 63;
    int lrow = lane & 15, lk = (lane >> 4) * 8;

    short8 af[4];
#pragma unroll
    for (int k = 0; k < 4; ++k)
        af[k] = *(const short8*)&As[(wid * 16 + lrow) * LDK + k * 32 + lk];

    floatx4 acc[8];
#pragma unroll
    for (int n = 0; n < 8; ++n) acc[n] = (floatx4){0.f, 0.f, 0.f, 0.f};
#pragma unroll
    for (int n = 0; n < 8; ++n)
#pragma unroll
        for (int k = 0; k < 4; ++k) {
            short8 bfr = *(const short8*)&Ws[(n * 16 + lrow) * LDK + k * 32 + lk];
            acc[n] = __builtin_amdgcn_mfma_f32_16x16x32_bf16(af[k], bfr, acc[n], 0, 0, 0);
        }

    __syncthreads();   // done reading As/Ws; about to overwrite As with relu(x)

    int orow = row0 + wid * 16 + (lane >> 4) * 4;
    int lrowbase = wid * 16 + (lane >> 4) * 4;
#pragma unroll
    for (int n = 0; n < 8; ++n) {
        int col = n * 16 + lrow;
        float bv = bias[col];
#pragma unroll
        for (int r = 0; r < 4; ++r) {
            int gr = orow + r;
            float v = acc[n][r] + bv;
            if (v < 0.f) v = 0.f;
            if (gr < M) Out[(long)gr * HID + col] = v;
            As[(lrowbase + r) * LDK + col] = f2bf(v);
        }
    }

    // head: y = X @ wpt' + bp
    for (int c = tid; c < 64 * 16; c += 256) {
        int r = c >> 4, cc = c & 15;
        uint4 v = ((const uint4*)wpt)[c];
        *(uint4*)&Ws[r * LDK + cc * 8] = v;
    }
    __syncthreads();
    short8 af2[4];
#pragma unroll
    for (int k = 0; k < 4; ++k)
        af2[k] = *(const short8*)&As[(wid * 16 + lrow) * LDK + k * 32 + lk];
    floatx4 acc2[4];
#pragma unroll
    for (int n = 0; n < 4; ++n) acc2[n] = (floatx4){0.f, 0.f, 0.f, 0.f};
#pragma unroll
    for (int n = 0; n < 4; ++n)
#pragma unroll
        for (int k = 0; k < 4; ++k) {
            short8 bfr = *(const short8*)&Ws[(n * 16 + lrow) * LDK + k * 32 + lk];
            acc2[n] = __builtin_amdgcn_mfma_f32_16x16x32_bf16(af2[k], bfr, acc2[n], 0, 0, 0);
        }
#pragma unroll
    for (int n = 0; n < 4; ++n) {
        int col = n * 16 + lrow;
        float bv = bp[col];
#pragma unroll
        for (int r = 0; r < 4; ++r) {
            int gr = orow + r;
            if (gr < M) yout[(long)gr * OUT_DIM + col] = acc2[n][r] + bv;
        }
    }
}

extern "C" void kernel_launch(void* const* d_in, const int* in_sizes, int n_in,
                              void* d_out, int out_size, void* d_ws, size_t ws_size,
                              hipStream_t stream) {
    const int*   x_ids    = (const int*)d_in[0];
    const int*   edge_src = (const int*)d_in[1];
    const int*   edge_dst = (const int*)d_in[2];
    const float* embed    = (const float*)d_in[3];
    const float* eps0     = (const float*)d_in[4];
    const float* w1_0     = (const float*)d_in[5];
    const float* b1_0     = (const float*)d_in[6];
    const float* w2_0     = (const float*)d_in[7];
    const float* b2_0     = (const float*)d_in[8];
    const float* eps1     = (const float*)d_in[9];
    const float* w1_1     = (const float*)d_in[10];
    const float* b1_1     = (const float*)d_in[11];
    const float* w2_1     = (const float*)d_in[12];
    const float* b2_1     = (const float*)d_in[13];
    const float* wp       = (const float*)d_in[14];
    const float* bp       = (const float*)d_in[15];

    float* out  = (float*)d_out;
    float* OUTX = out + (size_t)N_NODES * OUT_DIM;
    uint*  XB   = (uint*)out;   // y region doubles as bf16 feature buffer until the end

    char* ws = (char*)d_ws;
    size_t off = 0;
    uint* AGG  = (uint*)(ws + off);             off += (size_t)N_NODES * 64 * 4;
    uint* pairs= (uint*)(ws + off);             off += (size_t)NBUCK * CAPB * 4;
    uint* csr  = (uint*)(ws + off);             off += (size_t)NBUCK * CAPB * 4;
    int* row_start = (int*)(ws + off);          off += (size_t)N_NODES * 4;
    int* row_cnt   = (int*)(ws + off);          off += (size_t)N_NODES * 4;
    unsigned short* WfB0 = (unsigned short*)(ws + off); off += HID * HID * 2;
    unsigned short* WfB1 = (unsigned short*)(ws + off); off += HID * HID * 2;
    unsigned short* wpB  = (unsigned short*)(ws + off); off += OUT_DIM * HID * 2;
    float* Bf0 = (float*)(ws + off);            off += HID * 4;
    float* Bf1 = (float*)(ws + off);            off += HID * 4;
    int* tails = (int*)(ws + off);              off += NBUCK * 4;

    hipMemsetAsync(tails, 0, NBUCK * 4, stream);
    bucket_k<<<(N_EDGES + EPB - 1) / EPB, 256, 0, stream>>>(edge_src, edge_dst, x_ids,
                                                            tails, pairs);
    binsort_k<<<NBUCK, 256, 0, stream>>>(tails, pairs, csr, row_start, row_cnt);

    fusew_k<<<HID + 1, HID, 0, stream>>>(w1_0, b1_0, w2_0, b2_0, WfB0, Bf0);
    fusew_k<<<HID + 1, HID, 0, stream>>>(w1_1, b1_1, w2_1, b2_1, WfB1, Bf1);
    cvtwp_k<<<(OUT_DIM * HID + 255) / 256, 256, 0, stream>>>(wp, wpB);

    const int GB = (N_NODES + 63) / 64;
    // layer 0: fully fused (LDS-embed aggregation + GEMM) -> XB bf16
    gin0_k<<<GB, 256, 0, stream>>>(x_ids, embed, row_start, row_cnt, csr, eps0,
                                   WfB0, Bf0, (unsigned short*)XB, N_NODES);
    // layer 1: gather (global) + GEMM + fused head
    agg_k<<<N_NODES / 4, 256, 0, stream>>>(XB, AGG, row_start, row_cnt, csr, eps1);
    mgemm1_k<<<GB, 256, 0, stream>>>(AGG, WfB1, Bf1, OUTX, N_NODES, wpB, bp, out);
}

// Round 5
// 232.959 us; speedup vs baseline: 2.7873x; 1.0748x over previous
//
#include <hip/hip_runtime.h>

typedef short short8 __attribute__((ext_vector_type(8)));
typedef float floatx4 __attribute__((ext_vector_type(4)));
typedef unsigned int uint;

#define N_NODES 100000
#define N_EDGES 1600000
#define HID 128
#define OUT_DIM 64
#define VOCAB 28
#define NBUCK 196      // ceil(100000 / 512) buckets of 512 dst nodes
#define CAPB 10240     // per-bucket capacity (mean 8163, sigma ~90)
#define EPB 2048       // edges per block in bucket_k

// pairs entry: bits[0:16]=src, bits[17:25]=dst&511, bits[26:30]=vocab id
// csr entry:   bits[0:16]=src, bits[17:21]=vocab id of src

// ---------- bf16 helpers (RNE) ----------
__device__ inline unsigned short f2bf(float f) {
    union { float f; uint u; } v; v.f = f;
    uint r = v.u + 0x7FFFu + ((v.u >> 16) & 1u);
    return (unsigned short)(r >> 16);
}
__device__ inline uint pack2(float a, float b) {
    return (uint)f2bf(a) | ((uint)f2bf(b) << 16);
}
__device__ inline float2 bf2f(uint u) {
    union { uint u; float f; } a, b;
    a.u = u << 16; b.u = u & 0xFFFF0000u;
    return make_float2(a.f, b.f);
}

// ---------- pass A: bucket edges by dst>>9, tail-append runs ----------
__global__ __launch_bounds__(256) void bucket_k(const int* __restrict__ src,
                                                const int* __restrict__ dst,
                                                const int* __restrict__ ids,
                                                int* __restrict__ tails,
                                                uint* __restrict__ pairs) {
    __shared__ int lcnt[NBUCK];
    __shared__ int lbase[NBUCK];
    int tid = threadIdx.x;
    for (int i = tid; i < NBUCK; i += 256) lcnt[i] = 0;
    __syncthreads();
    int e0 = blockIdx.x * EPB;
    int b[8], p[8]; uint val[8];
#pragma unroll
    for (int k = 0; k < 8; ++k) {
        int e = e0 + k * 256 + tid;
        if (e < N_EDGES) {
            int d = dst[e], s = src[e];
            uint vid = (uint)ids[s];
            b[k] = d >> 9;
            val[k] = (uint)s | ((uint)(d & 511) << 17) | (vid << 26);
            p[k] = atomicAdd(&lcnt[b[k]], 1);
        } else b[k] = -1;
    }
    __syncthreads();
    for (int i = tid; i < NBUCK; i += 256)
        lbase[i] = (lcnt[i] > 0) ? atomicAdd(&tails[i], lcnt[i]) : 0;
    __syncthreads();
#pragma unroll
    for (int k = 0; k < 8; ++k) {
        if (b[k] >= 0) {
            int pos = lbase[b[k]] + p[k];
            if (pos < CAPB) pairs[b[k] * CAPB + pos] = val[k];
        }
    }
}

// ---------- pass B: per-bucket counting sort -> exact CSR ----------
__global__ __launch_bounds__(256) void binsort_k(const int* __restrict__ tails,
                                                 const uint* __restrict__ pairs,
                                                 uint* __restrict__ csr,
                                                 int* __restrict__ row_start,
                                                 int* __restrict__ row_cnt) {
    int b = blockIdx.x;
    int d0 = b << 9;
    int ne = tails[b]; if (ne > CAPB) ne = CAPB;
    __shared__ int cnt[512];
    __shared__ int pre[512];
    int tid = threadIdx.x;
    cnt[tid] = 0; cnt[tid + 256] = 0;
    __syncthreads();
    for (int i = tid; i < ne; i += 256)
        atomicAdd(&cnt[(pairs[b * CAPB + i] >> 17) & 511u], 1);
    __syncthreads();
    if (tid < 64) {
        int base = tid * 8;
        int loc[8]; int s = 0;
#pragma unroll
        for (int k = 0; k < 8; ++k) { loc[k] = s; s += cnt[base + k]; }
        int excl = s;
        for (int off = 1; off < 64; off <<= 1) {
            int v = __shfl_up(excl, off);
            if (tid >= off) excl += v;
        }
        excl -= s;
#pragma unroll
        for (int k = 0; k < 8; ++k) pre[base + k] = excl + loc[k];
    }
    __syncthreads();
    int gbase = b * CAPB;
    for (int i = tid; i < 512; i += 256) {
        int d = d0 + i;
        if (d < N_NODES) { row_start[d] = gbase + pre[i]; row_cnt[d] = cnt[i]; }
    }
    __syncthreads();
    for (int i = tid; i < ne; i += 256) {
        uint u = pairs[b * CAPB + i];
        int pos = atomicAdd(&pre[(u >> 17) & 511u], 1);
        csr[gbase + pos] = (u & 0x1FFFFu) | ((u >> 26) << 17);
    }
}

// ---------- fused weights: Wf = w1@w2 (f32 row-major + bf16 [col][k]), Bf = b1@w2+b2 ----------
__global__ __launch_bounds__(128) void fusew_k(const float* __restrict__ w1,
                                               const float* __restrict__ b1,
                                               const float* __restrict__ w2,
                                               const float* __restrict__ b2,
                                               float* __restrict__ Wf,
                                               unsigned short* __restrict__ WtB,
                                               float* __restrict__ Bf) {
    int j = threadIdx.x;
    int i = blockIdx.x;
    if (i < HID) {
        float s = 0.f;
        for (int k = 0; k < HID; ++k) s = fmaf(w1[i * HID + k], w2[k * HID + j], s);
        Wf[i * HID + j] = s;
        WtB[j * HID + i] = f2bf(s);
    } else {
        float s = b2[j];
        for (int k = 0; k < HID; ++k) s = fmaf(b1[k], w2[k * HID + j], s);
        Bf[j] = s;
    }
}

// ---------- EWt[j][kk] = bf16( sum_m emb[kk][m] * Wf0[m][j] ), kk in [0,32), zero-pad >=28 ----------
__global__ __launch_bounds__(256) void ewt_k(const float* __restrict__ emb,
                                             const float* __restrict__ Wf0,
                                             unsigned short* __restrict__ EWt) {
    int t = blockIdx.x * 256 + threadIdx.x;   // 4096 threads
    int j = t >> 5, kk = t & 31;
    float s = 0.f;
    if (kk < VOCAB)
        for (int m = 0; m < HID; ++m) s = fmaf(emb[kk * HID + m], Wf0[m * HID + j], s);
    EWt[j * 32 + kk] = f2bf(s);
}

__global__ __launch_bounds__(256) void cvtwp_k(const float* __restrict__ wp,
                                               unsigned short* __restrict__ wpB) {
    int i = blockIdx.x * 256 + threadIdx.x;
    if (i < OUT_DIM * HID) {
        int col = i / HID, k = i % HID;
        wpB[i] = f2bf(wp[k * OUT_DIM + col]);
    }
}

// ---------- layer-0 aggregation as vocab histogram: C[n][v] = #nbr(v) + (1+eps)[v==id_n] ----------
__global__ __launch_bounds__(256) void hist_k(const int* __restrict__ ids,
                                              const int* __restrict__ row_start,
                                              const int* __restrict__ row_cnt,
                                              const uint* __restrict__ csr,
                                              const float* __restrict__ epsp,
                                              unsigned short* __restrict__ C) {
    int node = blockIdx.x * 4 + (threadIdx.x >> 6);
    int lane = threadIdx.x & 63;
    int start = row_start[node], deg = row_cnt[node];
    int own = ids[node];
    int cnt = 0;
    for (int base = 0; base < deg; base += 64) {
        int m = deg - base; if (m > 64) m = 64;
        uint vid = (lane < m) ? (csr[start + base + lane] >> 17) : 0xFFFFu;
#pragma unroll
        for (int t = 0; t < VOCAB; ++t) {
            unsigned long long bl = __ballot(vid == (uint)t);
            if (lane == t) cnt += __popcll(bl);
        }
    }
    float myc = (float)cnt;
    if (lane == own) myc += 1.0f + epsp[0];
    if (lane < 32) C[node * 32 + lane] = f2bf((lane < VOCAB) ? myc : 0.f);
}

// ---------- layer-0 GEMM: XB = bf16(relu(C @ EWt' + Bf0)), K=32, no LDS ----------
__global__ __launch_bounds__(256) void gemm0_k(const unsigned short* __restrict__ C,
                                               const unsigned short* __restrict__ EWt,
                                               const float* __restrict__ bias,
                                               unsigned short* __restrict__ XB, int M) {
    int tid = threadIdx.x, wid = tid >> 6, lane = tid & 63;
    int row0 = blockIdx.x * 64;
    int lrow = lane & 15, lk = (lane >> 4) * 8;
    int arow = row0 + wid * 16 + lrow;
    short8 af = (short8){0,0,0,0,0,0,0,0};
    if (arow < M) af = *(const short8*)&C[arow * 32 + lk];

    floatx4 acc[8];
#pragma unroll
    for (int n = 0; n < 8; ++n) {
        short8 bfr = *(const short8*)&EWt[(n * 16 + lrow) * 32 + lk];
        acc[n] = __builtin_amdgcn_mfma_f32_16x16x32_bf16(af, bfr,
                                                         (floatx4){0.f,0.f,0.f,0.f}, 0, 0, 0);
    }
    int orow = row0 + wid * 16 + (lane >> 4) * 4;
#pragma unroll
    for (int n = 0; n < 8; ++n) {
        int col = n * 16 + lrow;
        float bv = bias[col];
#pragma unroll
        for (int r = 0; r < 4; ++r) {
            int gr = orow + r;
            if (gr < M) {
                float v = acc[n][r] + bv;
                if (v < 0.f) v = 0.f;
                XB[(long)gr * HID + col] = f2bf(v);
            }
        }
    }
}

// ---------- layer-1 aggregation: 2 srcs/wave-iter via uint2, deeper MLP ----------
__global__ __launch_bounds__(256) void agg_k(const uint* __restrict__ xb,
                                             uint* __restrict__ ob,
                                             const int* __restrict__ row_start,
                                             const int* __restrict__ row_cnt,
                                             const uint* __restrict__ csr,
                                             const float* __restrict__ epsp) {
    int node = blockIdx.x * 4 + (threadIdx.x >> 6);
    int lane = threadIdx.x & 63;
    int half = lane >> 5;        // 0: even srcs, 1: odd srcs
    int fl = lane & 31;          // uint2 feature index (8 B = 4 bf16)
    int start = row_start[node], deg = row_cnt[node];
    float e1 = 1.0f + epsp[0];
    const uint2* x2 = (const uint2*)xb;     // 32 uint2 per row
    float a0 = 0.f, a1 = 0.f, a2 = 0.f, a3 = 0.f;
    if (half == 0) {
        uint2 su = x2[(long)node * 32 + fl];
        float2 s0 = bf2f(su.x), s1 = bf2f(su.y);
        a0 = s0.x * e1; a1 = s0.y * e1; a2 = s1.x * e1; a3 = s1.y * e1;
    }
    for (int base = 0; base < deg; base += 64) {
        int m = deg - base; if (m > 64) m = 64;
        int my = (lane < m) ? (int)(csr[start + base + lane] & 0x1FFFFu) : 0;
        int j = 0;
        for (; j + 8 <= m; j += 8) {          // 4 pairs: 8 rows in flight across wave
            int i0 = __shfl(my, j + half),     i1 = __shfl(my, j + 2 + half);
            int i2 = __shfl(my, j + 4 + half), i3 = __shfl(my, j + 6 + half);
            uint2 u0 = x2[(long)i0 * 32 + fl], u1 = x2[(long)i1 * 32 + fl];
            uint2 u2 = x2[(long)i2 * 32 + fl], u3 = x2[(long)i3 * 32 + fl];
            float2 f0 = bf2f(u0.x), g0 = bf2f(u0.y), f1 = bf2f(u1.x), g1 = bf2f(u1.y);
            float2 f2 = bf2f(u2.x), g2 = bf2f(u2.y), f3 = bf2f(u3.x), g3 = bf2f(u3.y);
            a0 += (f0.x + f1.x) + (f2.x + f3.x);
            a1 += (f0.y + f1.y) + (f2.y + f3.y);
            a2 += (g0.x + g1.x) + (g2.x + g3.x);
            a3 += (g0.y + g1.y) + (g2.y + g3.y);
        }
        for (; j + 2 <= m; j += 2) {
            int i0 = __shfl(my, j + half);
            uint2 u = x2[(long)i0 * 32 + fl];
            float2 f = bf2f(u.x), g = bf2f(u.y);
            a0 += f.x; a1 += f.y; a2 += g.x; a3 += g.y;
        }
        if (j < m) {                          // odd tail: half 0 only
            int i0 = __shfl(my, j);
            if (half == 0) {
                uint2 u = x2[(long)i0 * 32 + fl];
                float2 f = bf2f(u.x), g = bf2f(u.y);
                a0 += f.x; a1 += f.y; a2 += g.x; a3 += g.y;
            }
        }
    }
    a0 += __shfl_xor(a0, 32); a1 += __shfl_xor(a1, 32);
    a2 += __shfl_xor(a2, 32); a3 += __shfl_xor(a3, 32);
    if (half == 0)
        ((uint2*)ob)[(long)node * 32 + fl] = make_uint2(pack2(a0, a1), pack2(a2, a3));
}

// ---------- layer-1 MFMA GEMM + fused head (A and W direct from global) ----------
__global__ __launch_bounds__(256) void mgemm1_k(const unsigned short* __restrict__ Ab,
                                                const unsigned short* __restrict__ Wt,
                                                const float* __restrict__ bias,
                                                float* __restrict__ Out, int M,
                                                const unsigned short* __restrict__ wpt,
                                                const float* __restrict__ bp,
                                                float* __restrict__ yout) {
    constexpr int LDK = HID + 8;
    __shared__ unsigned short As[64 * LDK];   // head handoff only (17.4 KB)
    int tid = threadIdx.x, wid = tid >> 6, lane = tid & 63;
    int row0 = blockIdx.x * 64;
    int lrow = lane & 15, lk = (lane >> 4) * 8;
    int arow = row0 + wid * 16 + lrow;
    bool av = arow < M;

    short8 af[4];
#pragma unroll
    for (int k = 0; k < 4; ++k)
        af[k] = av ? *(const short8*)&Ab[(long)arow * HID + k * 32 + lk]
                   : (short8){0,0,0,0,0,0,0,0};

    floatx4 acc[8];
#pragma unroll
    for (int n = 0; n < 8; ++n) acc[n] = (floatx4){0.f, 0.f, 0.f, 0.f};
#pragma unroll
    for (int n = 0; n < 8; ++n)
#pragma unroll
        for (int k = 0; k < 4; ++k) {
            short8 bfr = *(const short8*)&Wt[(n * 16 + lrow) * HID + k * 32 + lk];
            acc[n] = __builtin_amdgcn_mfma_f32_16x16x32_bf16(af[k], bfr, acc[n], 0, 0, 0);
        }

    int orow = row0 + wid * 16 + (lane >> 4) * 4;
    int lrowbase = wid * 16 + (lane >> 4) * 4;
#pragma unroll
    for (int n = 0; n < 8; ++n) {
        int col = n * 16 + lrow;
        float bv = bias[col];
#pragma unroll
        for (int r = 0; r < 4; ++r) {
            int gr = orow + r;
            float v = acc[n][r] + bv;
            if (v < 0.f) v = 0.f;
            if (gr < M) Out[(long)gr * HID + col] = v;
            As[(lrowbase + r) * LDK + col] = f2bf(v);
        }
    }
    __syncthreads();

    // head: y = X @ wpt' + bp
    short8 af2[4];
#pragma unroll
    for (int k = 0; k < 4; ++k)
        af2[k] = *(const short8*)&As[(wid * 16 + lrow) * LDK + k * 32 + lk];
    floatx4 acc2[4];
#pragma unroll
    for (int n = 0; n < 4; ++n) acc2[n] = (floatx4){0.f, 0.f, 0.f, 0.f};
#pragma unroll
    for (int n = 0; n < 4; ++n)
#pragma unroll
        for (int k = 0; k < 4; ++k) {
            short8 bfr = *(const short8*)&wpt[(n * 16 + lrow) * HID + k * 32 + lk];
            acc2[n] = __builtin_amdgcn_mfma_f32_16x16x32_bf16(af2[k], bfr, acc2[n], 0, 0, 0);
        }
#pragma unroll
    for (int n = 0; n < 4; ++n) {
        int col = n * 16 + lrow;
        float bv = bp[col];
#pragma unroll
        for (int r = 0; r < 4; ++r) {
            int gr = orow + r;
            if (gr < M) yout[(long)gr * OUT_DIM + col] = acc2[n][r] + bv;
        }
    }
}

extern "C" void kernel_launch(void* const* d_in, const int* in_sizes, int n_in,
                              void* d_out, int out_size, void* d_ws, size_t ws_size,
                              hipStream_t stream) {
    const int*   x_ids    = (const int*)d_in[0];
    const int*   edge_src = (const int*)d_in[1];
    const int*   edge_dst = (const int*)d_in[2];
    const float* embed    = (const float*)d_in[3];
    const float* eps0     = (const float*)d_in[4];
    const float* w1_0     = (const float*)d_in[5];
    const float* b1_0     = (const float*)d_in[6];
    const float* w2_0     = (const float*)d_in[7];
    const float* b2_0     = (const float*)d_in[8];
    const float* eps1     = (const float*)d_in[9];
    const float* w1_1     = (const float*)d_in[10];
    const float* b1_1     = (const float*)d_in[11];
    const float* w2_1     = (const float*)d_in[12];
    const float* b2_1     = (const float*)d_in[13];
    const float* wp       = (const float*)d_in[14];
    const float* bp       = (const float*)d_in[15];

    float* out  = (float*)d_out;
    float* OUTX = out + (size_t)N_NODES * OUT_DIM;
    uint*  XB   = (uint*)out;   // y region doubles as bf16 feature buffer until the end

    char* ws = (char*)d_ws;
    size_t off = 0;
    uint* AGG  = (uint*)(ws + off);             off += (size_t)N_NODES * 64 * 4;
    uint* pairs= (uint*)(ws + off);             off += (size_t)NBUCK * CAPB * 4;
    uint* csr  = (uint*)(ws + off);             off += (size_t)NBUCK * CAPB * 4;
    int* row_start = (int*)(ws + off);          off += (size_t)N_NODES * 4;
    int* row_cnt   = (int*)(ws + off);          off += (size_t)N_NODES * 4;
    float* Wf0f = (float*)(ws + off);           off += HID * HID * 4;
    float* Wf1f = (float*)(ws + off);           off += HID * HID * 4;
    unsigned short* WtB0 = (unsigned short*)(ws + off); off += HID * HID * 2;  // unused
    unsigned short* WtB1 = (unsigned short*)(ws + off); off += HID * HID * 2;
    unsigned short* wpB  = (unsigned short*)(ws + off); off += OUT_DIM * HID * 2;
    unsigned short* EWt  = (unsigned short*)(ws + off); off += HID * 32 * 2;
    float* Bf0 = (float*)(ws + off);            off += HID * 4;
    float* Bf1 = (float*)(ws + off);            off += HID * 4;
    int* tails = (int*)(ws + off);              off += NBUCK * 4;
    unsigned short* C = (unsigned short*)pairs; // [N][32] bf16, aliases pairs (dead after binsort)

    hipMemsetAsync(tails, 0, NBUCK * 4, stream);
    bucket_k<<<(N_EDGES + EPB - 1) / EPB, 256, 0, stream>>>(edge_src, edge_dst, x_ids,
                                                            tails, pairs);
    binsort_k<<<NBUCK, 256, 0, stream>>>(tails, pairs, csr, row_start, row_cnt);

    fusew_k<<<HID + 1, HID, 0, stream>>>(w1_0, b1_0, w2_0, b2_0, Wf0f, WtB0, Bf0);
    fusew_k<<<HID + 1, HID, 0, stream>>>(w1_1, b1_1, w2_1, b2_1, Wf1f, WtB1, Bf1);
    ewt_k<<<16, 256, 0, stream>>>(embed, Wf0f, EWt);
    cvtwp_k<<<(OUT_DIM * HID + 255) / 256, 256, 0, stream>>>(wp, wpB);

    const int GB = (N_NODES + 63) / 64;
    // layer 0: histogram + tiny K=32 GEMM -> XB bf16
    hist_k<<<N_NODES / 4, 256, 0, stream>>>(x_ids, row_start, row_cnt, csr, eps0, C);
    gemm0_k<<<GB, 256, 0, stream>>>(C, EWt, Bf0, (unsigned short*)XB, N_NODES);
    // layer 1: gather + GEMM + fused head
    agg_k<<<N_NODES / 4, 256, 0, stream>>>(XB, AGG, row_start, row_cnt, csr, eps1);
    mgemm1_k<<<GB, 256, 0, stream>>>((const unsigned short*)AGG, WtB1, Bf1,
                                     OUTX, N_NODES, wpB, bp, out);
}

// Round 6
// 213.983 us; speedup vs baseline: 3.0345x; 1.0887x over previous
//
#include <hip/hip_runtime.h>

typedef short short8 __attribute__((ext_vector_type(8)));
typedef float floatx4 __attribute__((ext_vector_type(4)));
typedef unsigned int uint;

#define N_NODES 100000
#define N_EDGES 1600000
#define HID 128
#define OUT_DIM 64
#define VOCAB 28
#define NBUCK 196      // ceil(100000 / 512) buckets of 512 dst nodes
#define CAPB 10240     // per-bucket capacity (mean 8163, sigma ~90)
#define EPB 2048       // edges per block in bucket_k

// pairs entry: bits[0:16]=src, bits[17:25]=dst&511, bits[26:30]=vocab id
// csr entry:   bits[0:16]=src, bits[17:21]=vocab id of src

// ---------- bf16 helpers (RNE) ----------
__device__ inline unsigned short f2bf(float f) {
    union { float f; uint u; } v; v.f = f;
    uint r = v.u + 0x7FFFu + ((v.u >> 16) & 1u);
    return (unsigned short)(r >> 16);
}
__device__ inline uint pack2(float a, float b) {
    return (uint)f2bf(a) | ((uint)f2bf(b) << 16);
}
__device__ inline float2 bf2f(uint u) {
    union { uint u; float f; } a, b;
    a.u = u << 16; b.u = u & 0xFFFF0000u;
    return make_float2(a.f, b.f);
}

// ---------- pass A: bucket edges by dst>>9, tail-append runs ----------
__global__ __launch_bounds__(256) void bucket_k(const int* __restrict__ src,
                                                const int* __restrict__ dst,
                                                const int* __restrict__ ids,
                                                int* __restrict__ tails,
                                                uint* __restrict__ pairs) {
    __shared__ int lcnt[NBUCK];
    __shared__ int lbase[NBUCK];
    int tid = threadIdx.x;
    for (int i = tid; i < NBUCK; i += 256) lcnt[i] = 0;
    __syncthreads();
    int e0 = blockIdx.x * EPB;
    int b[8], p[8]; uint val[8];
#pragma unroll
    for (int k = 0; k < 8; ++k) {
        int e = e0 + k * 256 + tid;
        if (e < N_EDGES) {
            int d = dst[e], s = src[e];
            uint vid = (uint)ids[s];
            b[k] = d >> 9;
            val[k] = (uint)s | ((uint)(d & 511) << 17) | (vid << 26);
            p[k] = atomicAdd(&lcnt[b[k]], 1);
        } else b[k] = -1;
    }
    __syncthreads();
    for (int i = tid; i < NBUCK; i += 256)
        lbase[i] = (lcnt[i] > 0) ? atomicAdd(&tails[i], lcnt[i]) : 0;
    __syncthreads();
#pragma unroll
    for (int k = 0; k < 8; ++k) {
        if (b[k] >= 0) {
            int pos = lbase[b[k]] + p[k];
            if (pos < CAPB) pairs[b[k] * CAPB + pos] = val[k];
        }
    }
}

// ---------- pass B: per-bucket counting sort -> exact CSR ----------
__global__ __launch_bounds__(256) void binsort_k(const int* __restrict__ tails,
                                                 const uint* __restrict__ pairs,
                                                 uint* __restrict__ csr,
                                                 int* __restrict__ row_start,
                                                 int* __restrict__ row_cnt) {
    int b = blockIdx.x;
    int d0 = b << 9;
    int ne = tails[b]; if (ne > CAPB) ne = CAPB;
    __shared__ int cnt[512];
    __shared__ int pre[512];
    int tid = threadIdx.x;
    cnt[tid] = 0; cnt[tid + 256] = 0;
    __syncthreads();
    for (int i = tid; i < ne; i += 256)
        atomicAdd(&cnt[(pairs[b * CAPB + i] >> 17) & 511u], 1);
    __syncthreads();
    if (tid < 64) {
        int base = tid * 8;
        int loc[8]; int s = 0;
#pragma unroll
        for (int k = 0; k < 8; ++k) { loc[k] = s; s += cnt[base + k]; }
        int excl = s;
        for (int off = 1; off < 64; off <<= 1) {
            int v = __shfl_up(excl, off);
            if (tid >= off) excl += v;
        }
        excl -= s;
#pragma unroll
        for (int k = 0; k < 8; ++k) pre[base + k] = excl + loc[k];
    }
    __syncthreads();
    int gbase = b * CAPB;
    for (int i = tid; i < 512; i += 256) {
        int d = d0 + i;
        if (d < N_NODES) { row_start[d] = gbase + pre[i]; row_cnt[d] = cnt[i]; }
    }
    __syncthreads();
    for (int i = tid; i < ne; i += 256) {
        uint u = pairs[b * CAPB + i];
        int pos = atomicAdd(&pre[(u >> 17) & 511u], 1);
        csr[gbase + pos] = (u & 0x1FFFFu) | ((u >> 26) << 17);
    }
}

// ---------- fused weights: Wf = w1@w2 (f32 row-major + bf16 [col][k]), Bf = b1@w2+b2 ----------
__global__ __launch_bounds__(128) void fusew_k(const float* __restrict__ w1,
                                               const float* __restrict__ b1,
                                               const float* __restrict__ w2,
                                               const float* __restrict__ b2,
                                               float* __restrict__ Wf,
                                               unsigned short* __restrict__ WtB,
                                               float* __restrict__ Bf) {
    int j = threadIdx.x;
    int i = blockIdx.x;
    if (i < HID) {
        float s = 0.f;
        for (int k = 0; k < HID; ++k) s = fmaf(w1[i * HID + k], w2[k * HID + j], s);
        Wf[i * HID + j] = s;
        WtB[j * HID + i] = f2bf(s);
    } else {
        float s = b2[j];
        for (int k = 0; k < HID; ++k) s = fmaf(b1[k], w2[k * HID + j], s);
        Bf[j] = s;
    }
}

// ---------- EWt[j][kk] = bf16( sum_m emb[kk][m] * Wf0[m][j] ), kk in [0,32), zero-pad >=28 ----------
__global__ __launch_bounds__(256) void ewt_k(const float* __restrict__ emb,
                                             const float* __restrict__ Wf0,
                                             unsigned short* __restrict__ EWt) {
    int t = blockIdx.x * 256 + threadIdx.x;   // 4096 threads
    int j = t >> 5, kk = t & 31;
    float s = 0.f;
    if (kk < VOCAB)
        for (int m = 0; m < HID; ++m) s = fmaf(emb[kk * HID + m], Wf0[m * HID + j], s);
    EWt[j * 32 + kk] = f2bf(s);
}

__global__ __launch_bounds__(256) void cvtwp_k(const float* __restrict__ wp,
                                               unsigned short* __restrict__ wpB) {
    int i = blockIdx.x * 256 + threadIdx.x;
    if (i < OUT_DIM * HID) {
        int col = i / HID, k = i % HID;
        wpB[i] = f2bf(wp[k * OUT_DIM + col]);
    }
}

// ---------- layer-0 aggregation as vocab histogram: C[n][v] = #nbr(v) + (1+eps)[v==id_n] ----------
__global__ __launch_bounds__(256) void hist_k(const int* __restrict__ ids,
                                              const int* __restrict__ row_start,
                                              const int* __restrict__ row_cnt,
                                              const uint* __restrict__ csr,
                                              const float* __restrict__ epsp,
                                              unsigned short* __restrict__ C) {
    int node = blockIdx.x * 4 + (threadIdx.x >> 6);
    int lane = threadIdx.x & 63;
    int start = row_start[node], deg = row_cnt[node];
    int own = ids[node];
    int cnt = 0;
    for (int base = 0; base < deg; base += 64) {
        int m = deg - base; if (m > 64) m = 64;
        uint vid = (lane < m) ? (csr[start + base + lane] >> 17) : 0xFFFFu;
#pragma unroll
        for (int t = 0; t < VOCAB; ++t) {
            unsigned long long bl = __ballot(vid == (uint)t);
            if (lane == t) cnt += __popcll(bl);
        }
    }
    float myc = (float)cnt;
    if (lane == own) myc += 1.0f + epsp[0];
    if (lane < 32) C[node * 32 + lane] = f2bf((lane < VOCAB) ? myc : 0.f);
}

// ---------- layer-0 GEMM: XB = bf16(relu(C @ EWt' + Bf0)), K=32, no LDS ----------
__global__ __launch_bounds__(256) void gemm0_k(const unsigned short* __restrict__ C,
                                               const unsigned short* __restrict__ EWt,
                                               const float* __restrict__ bias,
                                               unsigned short* __restrict__ XB, int M) {
    int tid = threadIdx.x, wid = tid >> 6, lane = tid & 63;
    int row0 = blockIdx.x * 64;
    int lrow = lane & 15, lk = (lane >> 4) * 8;
    int arow = row0 + wid * 16 + lrow;
    short8 af = (short8){0,0,0,0,0,0,0,0};
    if (arow < M) af = *(const short8*)&C[arow * 32 + lk];

    floatx4 acc[8];
#pragma unroll
    for (int n = 0; n < 8; ++n) {
        short8 bfr = *(const short8*)&EWt[(n * 16 + lrow) * 32 + lk];
        acc[n] = __builtin_amdgcn_mfma_f32_16x16x32_bf16(af, bfr,
                                                         (floatx4){0.f,0.f,0.f,0.f}, 0, 0, 0);
    }
    int orow = row0 + wid * 16 + (lane >> 4) * 4;
#pragma unroll
    for (int n = 0; n < 8; ++n) {
        int col = n * 16 + lrow;
        float bv = bias[col];
#pragma unroll
        for (int r = 0; r < 4; ++r) {
            int gr = orow + r;
            if (gr < M) {
                float v = acc[n][r] + bv;
                if (v < 0.f) v = 0.f;
                XB[(long)gr * HID + col] = f2bf(v);
            }
        }
    }
}

// ---------- layer-1 aggregation: 2 srcs/wave-iter via uint2 ----------
__global__ __launch_bounds__(256) void agg_k(const uint* __restrict__ xb,
                                             uint* __restrict__ ob,
                                             const int* __restrict__ row_start,
                                             const int* __restrict__ row_cnt,
                                             const uint* __restrict__ csr,
                                             const float* __restrict__ epsp) {
    int node = blockIdx.x * 4 + (threadIdx.x >> 6);
    int lane = threadIdx.x & 63;
    int half = lane >> 5;        // 0: even srcs, 1: odd srcs
    int fl = lane & 31;          // uint2 feature index (8 B = 4 bf16)
    int start = row_start[node], deg = row_cnt[node];
    float e1 = 1.0f + epsp[0];
    const uint2* x2 = (const uint2*)xb;     // 32 uint2 per row
    float a0 = 0.f, a1 = 0.f, a2 = 0.f, a3 = 0.f;
    if (half == 0) {
        uint2 su = x2[(long)node * 32 + fl];
        float2 s0 = bf2f(su.x), s1 = bf2f(su.y);
        a0 = s0.x * e1; a1 = s0.y * e1; a2 = s1.x * e1; a3 = s1.y * e1;
    }
    for (int base = 0; base < deg; base += 64) {
        int m = deg - base; if (m > 64) m = 64;
        int my = (lane < m) ? (int)(csr[start + base + lane] & 0x1FFFFu) : 0;
        int j = 0;
        for (; j + 8 <= m; j += 8) {
            int i0 = __shfl(my, j + half),     i1 = __shfl(my, j + 2 + half);
            int i2 = __shfl(my, j + 4 + half), i3 = __shfl(my, j + 6 + half);
            uint2 u0 = x2[(long)i0 * 32 + fl], u1 = x2[(long)i1 * 32 + fl];
            uint2 u2 = x2[(long)i2 * 32 + fl], u3 = x2[(long)i3 * 32 + fl];
            float2 f0 = bf2f(u0.x), g0 = bf2f(u0.y), f1 = bf2f(u1.x), g1 = bf2f(u1.y);
            float2 f2 = bf2f(u2.x), g2 = bf2f(u2.y), f3 = bf2f(u3.x), g3 = bf2f(u3.y);
            a0 += (f0.x + f1.x) + (f2.x + f3.x);
            a1 += (f0.y + f1.y) + (f2.y + f3.y);
            a2 += (g0.x + g1.x) + (g2.x + g3.x);
            a3 += (g0.y + g1.y) + (g2.y + g3.y);
        }
        for (; j + 2 <= m; j += 2) {
            int i0 = __shfl(my, j + half);
            uint2 u = x2[(long)i0 * 32 + fl];
            float2 f = bf2f(u.x), g = bf2f(u.y);
            a0 += f.x; a1 += f.y; a2 += g.x; a3 += g.y;
        }
        if (j < m) {
            int i0 = __shfl(my, j);
            if (half == 0) {
                uint2 u = x2[(long)i0 * 32 + fl];
                float2 f = bf2f(u.x), g = bf2f(u.y);
                a0 += f.x; a1 += f.y; a2 += g.x; a3 += g.y;
            }
        }
    }
    a0 += __shfl_xor(a0, 32); a1 += __shfl_xor(a1, 32);
    a2 += __shfl_xor(a2, 32); a3 += __shfl_xor(a3, 32);
    if (half == 0)
        ((uint2*)ob)[(long)node * 32 + fl] = make_uint2(pack2(a0, a1), pack2(a2, a3));
}

// ---------- layer-1 MFMA GEMM + fused head (W staged in LDS, A direct from global) ----------
__global__ __launch_bounds__(256) void mgemm1_k(const unsigned short* __restrict__ Ab,
                                                const unsigned short* __restrict__ Wt,
                                                const float* __restrict__ bias,
                                                float* __restrict__ Out, int M,
                                                const unsigned short* __restrict__ wpt,
                                                const float* __restrict__ bp,
                                                float* __restrict__ yout) {
    constexpr int LDK = HID + 8;
    __shared__ unsigned short As[64 * LDK];    // handoff buffer (17.4 KB)
    __shared__ unsigned short Ws[HID * LDK];   // staged weights (34.8 KB)
    int tid = threadIdx.x, wid = tid >> 6, lane = tid & 63;
    int row0 = blockIdx.x * 64;
    int lrow = lane & 15, lk = (lane >> 4) * 8;
    int arow = row0 + wid * 16 + lrow;
    bool av = arow < M;

    // A fragments direct from global (independent loads, hidden under W staging)
    short8 af[4];
#pragma unroll
    for (int k = 0; k < 4; ++k)
        af[k] = av ? *(const short8*)&Ab[(long)arow * HID + k * 32 + lk]
                   : (short8){0,0,0,0,0,0,0,0};

    // stage W1 (HID x HID bf16, k-major) into LDS
    for (int c = tid; c < HID * 16; c += 256) {
        int r = c >> 4, cc = c & 15;
        uint4 v = ((const uint4*)Wt)[c];
        *(uint4*)&Ws[r * LDK + cc * 8] = v;
    }
    __syncthreads();

    floatx4 acc[8];
#pragma unroll
    for (int n = 0; n < 8; ++n) acc[n] = (floatx4){0.f, 0.f, 0.f, 0.f};
#pragma unroll
    for (int n = 0; n < 8; ++n)
#pragma unroll
        for (int k = 0; k < 4; ++k) {
            short8 bfr = *(const short8*)&Ws[(n * 16 + lrow) * LDK + k * 32 + lk];
            acc[n] = __builtin_amdgcn_mfma_f32_16x16x32_bf16(af[k], bfr, acc[n], 0, 0, 0);
        }

    int orow = row0 + wid * 16 + (lane >> 4) * 4;
    int lrowbase = wid * 16 + (lane >> 4) * 4;
#pragma unroll
    for (int n = 0; n < 8; ++n) {
        int col = n * 16 + lrow;
        float bv = bias[col];
#pragma unroll
        for (int r = 0; r < 4; ++r) {
            int gr = orow + r;
            float v = acc[n][r] + bv;
            if (v < 0.f) v = 0.f;
            if (gr < M) Out[(long)gr * HID + col] = v;
            As[(lrowbase + r) * LDK + col] = f2bf(v);
        }
    }
    __syncthreads();   // Ws reads done + As handoff written

    // restage head weights wpt [64][HID] into Ws
    for (int c = tid; c < 64 * 16; c += 256) {
        int r = c >> 4, cc = c & 15;
        uint4 v = ((const uint4*)wpt)[c];
        *(uint4*)&Ws[r * LDK + cc * 8] = v;
    }
    __syncthreads();

    // head: y = X @ wpt' + bp
    short8 af2[4];
#pragma unroll
    for (int k = 0; k < 4; ++k)
        af2[k] = *(const short8*)&As[(wid * 16 + lrow) * LDK + k * 32 + lk];
    floatx4 acc2[4];
#pragma unroll
    for (int n = 0; n < 4; ++n) acc2[n] = (floatx4){0.f, 0.f, 0.f, 0.f};
#pragma unroll
    for (int n = 0; n < 4; ++n)
#pragma unroll
        for (int k = 0; k < 4; ++k) {
            short8 bfr = *(const short8*)&Ws[(n * 16 + lrow) * LDK + k * 32 + lk];
            acc2[n] = __builtin_amdgcn_mfma_f32_16x16x32_bf16(af2[k], bfr, acc2[n], 0, 0, 0);
        }
#pragma unroll
    for (int n = 0; n < 4; ++n) {
        int col = n * 16 + lrow;
        float bv = bp[col];
#pragma unroll
        for (int r = 0; r < 4; ++r) {
            int gr = orow + r;
            if (gr < M) yout[(long)gr * OUT_DIM + col] = acc2[n][r] + bv;
        }
    }
}

extern "C" void kernel_launch(void* const* d_in, const int* in_sizes, int n_in,
                              void* d_out, int out_size, void* d_ws, size_t ws_size,
                              hipStream_t stream) {
    const int*   x_ids    = (const int*)d_in[0];
    const int*   edge_src = (const int*)d_in[1];
    const int*   edge_dst = (const int*)d_in[2];
    const float* embed    = (const float*)d_in[3];
    const float* eps0     = (const float*)d_in[4];
    const float* w1_0     = (const float*)d_in[5];
    const float* b1_0     = (const float*)d_in[6];
    const float* w2_0     = (const float*)d_in[7];
    const float* b2_0     = (const float*)d_in[8];
    const float* eps1     = (const float*)d_in[9];
    const float* w1_1     = (const float*)d_in[10];
    const float* b1_1     = (const float*)d_in[11];
    const float* w2_1     = (const float*)d_in[12];
    const float* b2_1     = (const float*)d_in[13];
    const float* wp       = (const float*)d_in[14];
    const float* bp       = (const float*)d_in[15];

    float* out  = (float*)d_out;
    float* OUTX = out + (size_t)N_NODES * OUT_DIM;
    uint*  XB   = (uint*)out;   // y region doubles as bf16 feature buffer until the end

    char* ws = (char*)d_ws;
    size_t off = 0;
    uint* AGG  = (uint*)(ws + off);             off += (size_t)N_NODES * 64 * 4;
    uint* pairs= (uint*)(ws + off);             off += (size_t)NBUCK * CAPB * 4;
    uint* csr  = (uint*)(ws + off);             off += (size_t)NBUCK * CAPB * 4;
    int* row_start = (int*)(ws + off);          off += (size_t)N_NODES * 4;
    int* row_cnt   = (int*)(ws + off);          off += (size_t)N_NODES * 4;
    float* Wf0f = (float*)(ws + off);           off += HID * HID * 4;
    float* Wf1f = (float*)(ws + off);           off += HID * HID * 4;
    unsigned short* WtB0 = (unsigned short*)(ws + off); off += HID * HID * 2;  // unused
    unsigned short* WtB1 = (unsigned short*)(ws + off); off += HID * HID * 2;
    unsigned short* wpB  = (unsigned short*)(ws + off); off += OUT_DIM * HID * 2;
    unsigned short* EWt  = (unsigned short*)(ws + off); off += HID * 32 * 2;
    float* Bf0 = (float*)(ws + off);            off += HID * 4;
    float* Bf1 = (float*)(ws + off);            off += HID * 4;
    int* tails = (int*)(ws + off);              off += NBUCK * 4;
    unsigned short* C = (unsigned short*)pairs; // [N][32] bf16, aliases pairs (dead after binsort)

    hipMemsetAsync(tails, 0, NBUCK * 4, stream);
    bucket_k<<<(N_EDGES + EPB - 1) / EPB, 256, 0, stream>>>(edge_src, edge_dst, x_ids,
                                                            tails, pairs);
    binsort_k<<<NBUCK, 256, 0, stream>>>(tails, pairs, csr, row_start, row_cnt);

    fusew_k<<<HID + 1, HID, 0, stream>>>(w1_0, b1_0, w2_0, b2_0, Wf0f, WtB0, Bf0);
    fusew_k<<<HID + 1, HID, 0, stream>>>(w1_1, b1_1, w2_1, b2_1, Wf1f, WtB1, Bf1);
    ewt_k<<<16, 256, 0, stream>>>(embed, Wf0f, EWt);
    cvtwp_k<<<(OUT_DIM * HID + 255) / 256, 256, 0, stream>>>(wp, wpB);

    const int GB = (N_NODES + 63) / 64;
    // layer 0: histogram + tiny K=32 GEMM -> XB bf16
    hist_k<<<N_NODES / 4, 256, 0, stream>>>(x_ids, row_start, row_cnt, csr, eps0, C);
    gemm0_k<<<GB, 256, 0, stream>>>(C, EWt, Bf0, (unsigned short*)XB, N_NODES);
    // layer 1: gather + GEMM + fused head
    agg_k<<<N_NODES / 4, 256, 0, stream>>>(XB, AGG, row_start, row_cnt, csr, eps1);
    mgemm1_k<<<GB, 256, 0, stream>>>((const unsigned short*)AGG, WtB1, Bf1,
                                     OUTX, N_NODES, wpB, bp, out);
}

// Round 7
// 171.335 us; speedup vs baseline: 3.7898x; 1.2489x over previous
//
#include <hip/hip_runtime.h>

typedef short short8 __attribute__((ext_vector_type(8)));
typedef float floatx4 __attribute__((ext_vector_type(4)));
typedef unsigned int uint;

#define N_NODES 100000
#define N_EDGES 1600000
#define HID 128
#define OUT_DIM 64
#define VOCAB 28
#define NBUCK 196      // ceil(100000 / 512) buckets of 512 dst nodes
#define CAPB 10240     // per-bucket capacity (mean 8163, sigma ~90)
#define EPB 4096       // edges per block in bucket_k

// pairs entry: bits[0:16]=src, bits[17:25]=dst&511, bits[26:30]=vocab id
// csr entry:   src node id

// ---------- bf16 helpers (RNE) ----------
__device__ inline unsigned short f2bf(float f) {
    union { float f; uint u; } v; v.f = f;
    uint r = v.u + 0x7FFFu + ((v.u >> 16) & 1u);
    return (unsigned short)(r >> 16);
}
__device__ inline uint pack2(float a, float b) {
    return (uint)f2bf(a) | ((uint)f2bf(b) << 16);
}
__device__ inline float2 bf2f(uint u) {
    union { uint u; float f; } a, b;
    a.u = u << 16; b.u = u & 0xFFFF0000u;
    return make_float2(a.f, b.f);
}

// ---------- combined weight prep (one kernel, 128-thread blocks) ----------
// blocks 0..128   : layer-1 fused weights WtB1 (+ Bf1 at block 128)
// block 129       : Bf0
// blocks 130..157 : EWt rows (kk = bid-130): EWt[j][kk] = (emb@w1_0@w2_0)[kk][j]
// blocks 158..221 : wp -> bf16 transposed
// block 222       : zero tails + EWt pad cols
__global__ __launch_bounds__(128) void prep_k(const float* __restrict__ embed,
                                              const float* __restrict__ w1_0,
                                              const float* __restrict__ b1_0,
                                              const float* __restrict__ w2_0,
                                              const float* __restrict__ b2_0,
                                              const float* __restrict__ w1_1,
                                              const float* __restrict__ b1_1,
                                              const float* __restrict__ w2_1,
                                              const float* __restrict__ b2_1,
                                              const float* __restrict__ wp,
                                              unsigned short* __restrict__ WtB1,
                                              float* __restrict__ Bf1,
                                              float* __restrict__ Bf0,
                                              unsigned short* __restrict__ EWt,
                                              unsigned short* __restrict__ wpB,
                                              int* __restrict__ tails) {
    int bid = blockIdx.x, j = threadIdx.x;
    if (bid < 128) {                     // WtB1 row i
        int i = bid;
        float s = 0.f;
        for (int k = 0; k < HID; ++k) s = fmaf(w1_1[i * HID + k], w2_1[k * HID + j], s);
        WtB1[j * HID + i] = f2bf(s);
    } else if (bid == 128) {             // Bf1
        float s = b2_1[j];
        for (int k = 0; k < HID; ++k) s = fmaf(b1_1[k], w2_1[k * HID + j], s);
        Bf1[j] = s;
    } else if (bid == 129) {             // Bf0
        float s = b2_0[j];
        for (int k = 0; k < HID; ++k) s = fmaf(b1_0[k], w2_0[k * HID + j], s);
        Bf0[j] = s;
    } else if (bid < 158) {              // EWt, kk = bid-130
        int kk = bid - 130;
        __shared__ float T[HID];
        float s = 0.f;
        for (int m = 0; m < HID; ++m) s = fmaf(embed[kk * HID + m], w1_0[m * HID + j], s);
        T[j] = s;
        __syncthreads();
        float s2 = 0.f;
        for (int k = 0; k < HID; ++k) s2 = fmaf(T[k], w2_0[k * HID + j], s2);
        EWt[j * 32 + kk] = f2bf(s2);
    } else if (bid < 222) {              // cvtwp
        int i = (bid - 158) * 128 + j;   // i = col*HID + k
        int col = i / HID, k = i % HID;
        wpB[i] = f2bf(wp[k * OUT_DIM + col]);
    } else {                             // zeros
        if (j < 128) { ((uint*)EWt)[j * 16 + 14] = 0u; ((uint*)EWt)[j * 16 + 15] = 0u; }
        for (int i = j; i < NBUCK; i += 128) tails[i] = 0;
    }
}

// ---------- pass A: bucket edges by dst>>9, tail-append runs ----------
__global__ __launch_bounds__(256) void bucket_k(const int* __restrict__ src,
                                                const int* __restrict__ dst,
                                                const int* __restrict__ ids,
                                                int* __restrict__ tails,
                                                uint* __restrict__ pairs) {
    __shared__ int lcnt[NBUCK];
    __shared__ int lbase[NBUCK];
    int tid = threadIdx.x;
    for (int i = tid; i < NBUCK; i += 256) lcnt[i] = 0;
    __syncthreads();
    int e0 = blockIdx.x * EPB;
    int b[16], p[16]; uint val[16];
#pragma unroll
    for (int k = 0; k < 16; ++k) {
        int e = e0 + k * 256 + tid;
        if (e < N_EDGES) {
            int d = dst[e], s = src[e];
            uint vid = (uint)ids[s];
            b[k] = d >> 9;
            val[k] = (uint)s | ((uint)(d & 511) << 17) | (vid << 26);
            p[k] = atomicAdd(&lcnt[b[k]], 1);
        } else b[k] = -1;
    }
    __syncthreads();
    for (int i = tid; i < NBUCK; i += 256)
        lbase[i] = (lcnt[i] > 0) ? atomicAdd(&tails[i], lcnt[i]) : 0;
    __syncthreads();
#pragma unroll
    for (int k = 0; k < 16; ++k) {
        if (b[k] >= 0) {
            int pos = lbase[b[k]] + p[k];
            if (pos < CAPB) pairs[b[k] * CAPB + pos] = val[k];
        }
    }
}

// ---------- pass B: counting sort -> CSR, + vocab histogram -> C ----------
__global__ __launch_bounds__(256) void binsort_k(const int* __restrict__ tails,
                                                 const uint* __restrict__ pairs,
                                                 uint* __restrict__ csr,
                                                 int* __restrict__ row_start,
                                                 int* __restrict__ row_cnt,
                                                 const int* __restrict__ ids,
                                                 const float* __restrict__ epsp,
                                                 unsigned short* __restrict__ C) {
    int b = blockIdx.x;
    int d0 = b << 9;
    int ne = tails[b]; if (ne > CAPB) ne = CAPB;
    __shared__ int cnt[512];
    __shared__ int pre[512];
    __shared__ uint hist[512 * 14];   // 28 KB: 2 vocab counts (16-bit) per word
    int tid = threadIdx.x;
    cnt[tid] = 0; cnt[tid + 256] = 0;
    for (int i = tid; i < 512 * 14; i += 256) hist[i] = 0u;
    __syncthreads();
    for (int i = tid; i < ne; i += 256) {
        uint u = pairs[b * CAPB + i];
        uint ln = (u >> 17) & 511u;
        uint v = u >> 26;
        atomicAdd(&cnt[ln], 1);
        atomicAdd(&hist[ln * 14 + (v >> 1)], 1u << ((v & 1u) * 16));
    }
    __syncthreads();
    if (tid < 64) {
        int base = tid * 8;
        int loc[8]; int s = 0;
#pragma unroll
        for (int k = 0; k < 8; ++k) { loc[k] = s; s += cnt[base + k]; }
        int excl = s;
        for (int off = 1; off < 64; off <<= 1) {
            int v = __shfl_up(excl, off);
            if (tid >= off) excl += v;
        }
        excl -= s;
#pragma unroll
        for (int k = 0; k < 8; ++k) pre[base + k] = excl + loc[k];
    }
    __syncthreads();
    int gbase = b * CAPB;
    for (int i = tid; i < 512; i += 256) {
        int d = d0 + i;
        if (d < N_NODES) { row_start[d] = gbase + pre[i]; row_cnt[d] = cnt[i]; }
    }
    __syncthreads();
    for (int i = tid; i < ne; i += 256) {
        uint u = pairs[b * CAPB + i];
        int pos = atomicAdd(&pre[(u >> 17) & 511u], 1);
        csr[gbase + pos] = u & 0x1FFFFu;
    }
    // emit C[n][32] bf16 (counts + (1+eps) self term)
    float e1 = 1.0f + epsp[0];
    for (int i = tid; i < 512 * 16; i += 256) {
        int ln = i >> 4, w = i & 15;
        int d = d0 + ln;
        if (d < N_NODES) {
            float c0 = 0.f, c1 = 0.f;
            if (w < 14) {
                uint h = hist[ln * 14 + w];
                c0 = (float)(h & 0xFFFFu);
                c1 = (float)(h >> 16);
            }
            int own = ids[d];
            if (own == 2 * w)     c0 += e1;
            if (own == 2 * w + 1) c1 += e1;
            ((uint*)C)[(long)d * 16 + w] = pack2(c0, c1);
        }
    }
}

// ---------- layer-0 GEMM: XB = bf16(relu(C @ EWt' + Bf0)), K=32, no LDS ----------
__global__ __launch_bounds__(256) void gemm0_k(const unsigned short* __restrict__ C,
                                               const unsigned short* __restrict__ EWt,
                                               const float* __restrict__ bias,
                                               unsigned short* __restrict__ XB, int M) {
    int tid = threadIdx.x, wid = tid >> 6, lane = tid & 63;
    int row0 = blockIdx.x * 64;
    int lrow = lane & 15, lk = (lane >> 4) * 8;
    int arow = row0 + wid * 16 + lrow;
    short8 af = (short8){0,0,0,0,0,0,0,0};
    if (arow < M) af = *(const short8*)&C[arow * 32 + lk];

    floatx4 acc[8];
#pragma unroll
    for (int n = 0; n < 8; ++n) {
        short8 bfr = *(const short8*)&EWt[(n * 16 + lrow) * 32 + lk];
        acc[n] = __builtin_amdgcn_mfma_f32_16x16x32_bf16(af, bfr,
                                                         (floatx4){0.f,0.f,0.f,0.f}, 0, 0, 0);
    }
    int orow = row0 + wid * 16 + (lane >> 4) * 4;
#pragma unroll
    for (int n = 0; n < 8; ++n) {
        int col = n * 16 + lrow;
        float bv = bias[col];
#pragma unroll
        for (int r = 0; r < 4; ++r) {
            int gr = orow + r;
            if (gr < M) {
                float v = acc[n][r] + bv;
                if (v < 0.f) v = 0.f;
                XB[(long)gr * HID + col] = f2bf(v);
            }
        }
    }
}

// ---------- layer-1 aggregation: uint4 loads, 4 rows / load instruction ----------
__global__ __launch_bounds__(256) void agg_k(const uint4* __restrict__ x4,
                                             uint4* __restrict__ ob4,
                                             const int* __restrict__ row_start,
                                             const int* __restrict__ row_cnt,
                                             const uint* __restrict__ csr,
                                             const float* __restrict__ epsp) {
    int node = blockIdx.x * 4 + (threadIdx.x >> 6);
    int lane = threadIdx.x & 63;
    int q = lane >> 4;            // row group 0..3
    int fl = lane & 15;           // uint4 index within row (16 x 16B = 256B)
    int start = row_start[node], deg = row_cnt[node];
    float e1 = 1.0f + epsp[0];
    float a0=0.f,a1=0.f,a2=0.f,a3=0.f,a4=0.f,a5=0.f,a6=0.f,a7=0.f;
#define ACC4(u) { float2 t0=bf2f((u).x),t1=bf2f((u).y),t2=bf2f((u).z),t3=bf2f((u).w); \
    a0+=t0.x; a1+=t0.y; a2+=t1.x; a3+=t1.y; a4+=t2.x; a5+=t2.y; a6+=t3.x; a7+=t3.y; }
    if (q == 0) {
        uint4 u = x4[(long)node * 16 + fl];
        float2 t0=bf2f(u.x),t1=bf2f(u.y),t2=bf2f(u.z),t3=bf2f(u.w);
        a0=t0.x*e1; a1=t0.y*e1; a2=t1.x*e1; a3=t1.y*e1;
        a4=t2.x*e1; a5=t2.y*e1; a6=t3.x*e1; a7=t3.y*e1;
    }
    for (int base = 0; base < deg; base += 64) {
        int m = deg - base; if (m > 64) m = 64;
        int my = (lane < m) ? (int)(csr[start + base + lane] & 0x1FFFFu) : 0;
        int j = 0;
        for (; j + 16 <= m; j += 16) {        // 16 rows in flight (4 loads/lane-group)
            int i0 = __shfl(my, j + q),      i1 = __shfl(my, j + 4 + q);
            int i2 = __shfl(my, j + 8 + q),  i3 = __shfl(my, j + 12 + q);
            uint4 u0 = x4[(long)i0 * 16 + fl], u1 = x4[(long)i1 * 16 + fl];
            uint4 u2 = x4[(long)i2 * 16 + fl], u3 = x4[(long)i3 * 16 + fl];
            ACC4(u0); ACC4(u1); ACC4(u2); ACC4(u3);
        }
        for (; j + 4 <= m; j += 4) {
            int i0 = __shfl(my, j + q);
            uint4 u = x4[(long)i0 * 16 + fl];
            ACC4(u);
        }
        if (j < m) {                          // tail 1..3 rows: groups q < m-j
            int i0 = __shfl(my, j + q);
            if (q < m - j) {
                uint4 u = x4[(long)i0 * 16 + fl];
                ACC4(u);
            }
        }
    }
#undef ACC4
    a0 += __shfl_xor(a0,16); a1 += __shfl_xor(a1,16); a2 += __shfl_xor(a2,16); a3 += __shfl_xor(a3,16);
    a4 += __shfl_xor(a4,16); a5 += __shfl_xor(a5,16); a6 += __shfl_xor(a6,16); a7 += __shfl_xor(a7,16);
    a0 += __shfl_xor(a0,32); a1 += __shfl_xor(a1,32); a2 += __shfl_xor(a2,32); a3 += __shfl_xor(a3,32);
    a4 += __shfl_xor(a4,32); a5 += __shfl_xor(a5,32); a6 += __shfl_xor(a6,32); a7 += __shfl_xor(a7,32);
    if (q == 0)
        ob4[(long)node * 16 + fl] = make_uint4(pack2(a0,a1), pack2(a2,a3),
                                               pack2(a4,a5), pack2(a6,a7));
}

// ---------- layer-1 MFMA GEMM + fused head (W staged in LDS, A direct from global) ----------
__global__ __launch_bounds__(256) void mgemm1_k(const unsigned short* __restrict__ Ab,
                                                const unsigned short* __restrict__ Wt,
                                                const float* __restrict__ bias,
                                                float* __restrict__ Out, int M,
                                                const unsigned short* __restrict__ wpt,
                                                const float* __restrict__ bp,
                                                float* __restrict__ yout) {
    constexpr int LDK = HID + 8;
    __shared__ unsigned short As[64 * LDK];    // handoff buffer (17.4 KB)
    __shared__ unsigned short Ws[HID * LDK];   // staged weights (34.8 KB)
    int tid = threadIdx.x, wid = tid >> 6, lane = tid & 63;
    int row0 = blockIdx.x * 64;
    int lrow = lane & 15, lk = (lane >> 4) * 8;
    int arow = row0 + wid * 16 + lrow;
    bool av = arow < M;

    short8 af[4];
#pragma unroll
    for (int k = 0; k < 4; ++k)
        af[k] = av ? *(const short8*)&Ab[(long)arow * HID + k * 32 + lk]
                   : (short8){0,0,0,0,0,0,0,0};

    for (int c = tid; c < HID * 16; c += 256) {
        int r = c >> 4, cc = c & 15;
        uint4 v = ((const uint4*)Wt)[c];
        *(uint4*)&Ws[r * LDK + cc * 8] = v;
    }
    __syncthreads();

    floatx4 acc[8];
#pragma unroll
    for (int n = 0; n < 8; ++n) acc[n] = (floatx4){0.f, 0.f, 0.f, 0.f};
#pragma unroll
    for (int n = 0; n < 8; ++n)
#pragma unroll
        for (int k = 0; k < 4; ++k) {
            short8 bfr = *(const short8*)&Ws[(n * 16 + lrow) * LDK + k * 32 + lk];
            acc[n] = __builtin_amdgcn_mfma_f32_16x16x32_bf16(af[k], bfr, acc[n], 0, 0, 0);
        }

    int orow = row0 + wid * 16 + (lane >> 4) * 4;
    int lrowbase = wid * 16 + (lane >> 4) * 4;
#pragma unroll
    for (int n = 0; n < 8; ++n) {
        int col = n * 16 + lrow;
        float bv = bias[col];
#pragma unroll
        for (int r = 0; r < 4; ++r) {
            int gr = orow + r;
            float v = acc[n][r] + bv;
            if (v < 0.f) v = 0.f;
            if (gr < M) Out[(long)gr * HID + col] = v;
            As[(lrowbase + r) * LDK + col] = f2bf(v);
        }
    }
    __syncthreads();

    for (int c = tid; c < 64 * 16; c += 256) {
        int r = c >> 4, cc = c & 15;
        uint4 v = ((const uint4*)wpt)[c];
        *(uint4*)&Ws[r * LDK + cc * 8] = v;
    }
    __syncthreads();

    short8 af2[4];
#pragma unroll
    for (int k = 0; k < 4; ++k)
        af2[k] = *(const short8*)&As[(wid * 16 + lrow) * LDK + k * 32 + lk];
    floatx4 acc2[4];
#pragma unroll
    for (int n = 0; n < 4; ++n) acc2[n] = (floatx4){0.f, 0.f, 0.f, 0.f};
#pragma unroll
    for (int n = 0; n < 4; ++n)
#pragma unroll
        for (int k = 0; k < 4; ++k) {
            short8 bfr = *(const short8*)&Ws[(n * 16 + lrow) * LDK + k * 32 + lk];
            acc2[n] = __builtin_amdgcn_mfma_f32_16x16x32_bf16(af2[k], bfr, acc2[n], 0, 0, 0);
        }
#pragma unroll
    for (int n = 0; n < 4; ++n) {
        int col = n * 16 + lrow;
        float bv = bp[col];
#pragma unroll
        for (int r = 0; r < 4; ++r) {
            int gr = orow + r;
            if (gr < M) yout[(long)gr * OUT_DIM + col] = acc2[n][r] + bv;
        }
    }
}

extern "C" void kernel_launch(void* const* d_in, const int* in_sizes, int n_in,
                              void* d_out, int out_size, void* d_ws, size_t ws_size,
                              hipStream_t stream) {
    const int*   x_ids    = (const int*)d_in[0];
    const int*   edge_src = (const int*)d_in[1];
    const int*   edge_dst = (const int*)d_in[2];
    const float* embed    = (const float*)d_in[3];
    const float* eps0     = (const float*)d_in[4];
    const float* w1_0     = (const float*)d_in[5];
    const float* b1_0     = (const float*)d_in[6];
    const float* w2_0     = (const float*)d_in[7];
    const float* b2_0     = (const float*)d_in[8];
    const float* eps1     = (const float*)d_in[9];
    const float* w1_1     = (const float*)d_in[10];
    const float* b1_1     = (const float*)d_in[11];
    const float* w2_1     = (const float*)d_in[12];
    const float* b2_1     = (const float*)d_in[13];
    const float* wp       = (const float*)d_in[14];
    const float* bp       = (const float*)d_in[15];

    float* out  = (float*)d_out;
    float* OUTX = out + (size_t)N_NODES * OUT_DIM;
    uint*  XB   = (uint*)out;   // y region doubles as bf16 feature buffer until the end

    char* ws = (char*)d_ws;
    size_t off = 0;
    uint* AGG  = (uint*)(ws + off);             off += (size_t)N_NODES * 64 * 4;
    uint* pairs= (uint*)(ws + off);             off += (size_t)NBUCK * CAPB * 4;
    uint* csr  = (uint*)(ws + off);             off += (size_t)NBUCK * CAPB * 4;
    int* row_start = (int*)(ws + off);          off += (size_t)N_NODES * 4;
    int* row_cnt   = (int*)(ws + off);          off += (size_t)N_NODES * 4;
    unsigned short* WtB1 = (unsigned short*)(ws + off); off += HID * HID * 2;
    unsigned short* wpB  = (unsigned short*)(ws + off); off += OUT_DIM * HID * 2;
    unsigned short* EWt  = (unsigned short*)(ws + off); off += HID * 32 * 2;
    float* Bf0 = (float*)(ws + off);            off += HID * 4;
    float* Bf1 = (float*)(ws + off);            off += HID * 4;
    int* tails = (int*)(ws + off);              off += NBUCK * 4;
    // C[n][32] bf16 aliases the head of AGG: written by binsort, read by gemm0,
    // then AGG is fully overwritten by agg_k (C dead by then).
    unsigned short* C = (unsigned short*)AGG;

    prep_k<<<223, 128, 0, stream>>>(embed, w1_0, b1_0, w2_0, b2_0,
                                    w1_1, b1_1, w2_1, b2_1, wp,
                                    WtB1, Bf1, Bf0, EWt, wpB, tails);
    bucket_k<<<(N_EDGES + EPB - 1) / EPB, 256, 0, stream>>>(edge_src, edge_dst, x_ids,
                                                            tails, pairs);
    binsort_k<<<NBUCK, 256, 0, stream>>>(tails, pairs, csr, row_start, row_cnt,
                                         x_ids, eps0, C);

    const int GB = (N_NODES + 63) / 64;
    gemm0_k<<<GB, 256, 0, stream>>>(C, EWt, Bf0, (unsigned short*)XB, N_NODES);
    agg_k<<<N_NODES / 4, 256, 0, stream>>>((const uint4*)XB, (uint4*)AGG,
                                           row_start, row_cnt, csr, eps1);
    mgemm1_k<<<GB, 256, 0, stream>>>((const unsigned short*)AGG, WtB1, Bf1,
                                     OUTX, N_NODES, wpB, bp, out);
}